// Round 4
// baseline (451.828 us; speedup 1.0000x reference)
//
#include <hip/hip_runtime.h>
#include <cmath>

#define DIM 1024
#define DIM_INNER 2048
#define BATCH 4
#define SEQ 4096
#define MTOT (BATCH * SEQ)
#define CHUNK 32
#define NCHUNK (SEQ / CHUNK)        // 128 chunks per sequence

typedef __bf16 bf16x8 __attribute__((ext_vector_type(8)));
typedef short short8_t __attribute__((ext_vector_type(8)));
typedef float floatx4 __attribute__((ext_vector_type(4)));
typedef unsigned short u16x4 __attribute__((ext_vector_type(4)));
typedef unsigned int uint4_t __attribute__((ext_vector_type(4)));
typedef float float4_t __attribute__((ext_vector_type(4)));
typedef unsigned short ushort_t;

template <int N> struct IC { static constexpr int v = N; };
template <bool B> struct BC { static constexpr bool v = B; };

#define LGKM_SB(n) do { asm volatile("s_waitcnt lgkmcnt(" #n ")" ::: "memory"); \
                        __builtin_amdgcn_sched_barrier(0); } while (0)
#define SCHED0() __builtin_amdgcn_sched_barrier(0)
#define SBAR() __builtin_amdgcn_s_barrier()

__device__ __forceinline__ unsigned short f2bf(float f) {
  unsigned int u = __builtin_bit_cast(unsigned int, f);
  u += 0x7fffu + ((u >> 16) & 1u);   // round-to-nearest-even
  return (unsigned short)(u >> 16);
}
__device__ __forceinline__ float bflo2f(unsigned int u) {
  return __builtin_bit_cast(float, u << 16);
}
__device__ __forceinline__ float bfhi2f(unsigned int u) {
  return __builtin_bit_cast(float, u & 0xffff0000u);
}

// Fast (native v_exp/v_log) log-space terms from (h, g):
//   lc = -softplus(g) ;  lv = -softplus(-g) + log_g(h) = g + lc + log_g(h)
__device__ __forceinline__ void lclv_fast(float h, float g, float& lc, float& lv) {
  float eg = __expf(-fabsf(g));
  float sp = fmaxf(g, 0.f) + __logf(1.f + eg);
  lc = -sp;
  float eh = __expf(h);
  float t  = (h >= 0.f) ? (h + 0.5f) : (1.f + eh);
  float lt = __logf(t);
  float lg = (h >= 0.f) ? lt : (h - lt);
  lv = g + lc + lg;
}
// a may be -inf; b finite
__device__ __forceinline__ float logaddexp_f(float a, float b) {
  float m = fmaxf(a, b);
  return m + __logf(1.f + __expf(-fabsf(a - b)));
}

// async 16B/lane global->LDS; dest = wave-uniform base + lane*16
__device__ __forceinline__ void async_copy16(const ushort_t* g, ushort_t* l) {
  __builtin_amdgcn_global_load_lds(
      (const __attribute__((address_space(1))) void*)g,
      (__attribute__((address_space(3))) void*)l, 16, 0, 0);
}

// ---------------------------------------------------------------------------
// One-time input conversions
// ---------------------------------------------------------------------------
__global__ __launch_bounds__(256) void convert_f32_bf16(
    const float* __restrict__ src, ushort_t* __restrict__ dst) {
  int i = blockIdx.x * 256 + threadIdx.x;   // one float4 per thread
  float4 v = ((const float4*)src)[i];
  u16x4 o = {f2bf(v.x), f2bf(v.y), f2bf(v.z), f2bf(v.w)};
  ((u16x4*)dst)[i] = o;
}

// dst[n][k] = bf16(src[k][n]); src is [K][N] fp32
__global__ __launch_bounds__(256) void transpose_f32_bf16(
    const float* __restrict__ src, ushort_t* __restrict__ dst, int K, int N) {
  __shared__ float tile[32][33];
  int tx = threadIdx.x & 31, ty = threadIdx.x >> 5;   // 32 x 8
  int n0 = blockIdx.x * 32, k0 = blockIdx.y * 32;
#pragma unroll
  for (int i = 0; i < 4; i++) {
    int k = ty + i * 8;
    tile[k][tx] = src[(size_t)(k0 + k) * N + n0 + tx];
  }
  __syncthreads();
#pragma unroll
  for (int i = 0; i < 4; i++) {
    int r = ty + i * 8;
    dst[(size_t)(n0 + r) * K + k0 + tx] = f2bf(tile[tx][r]);
  }
}

// ---------------------------------------------------------------------------
// GEMM1 fused — 256x(128h+128g), 8-wave, 4 phases/K-tile, BK=64.
// (a) bijective XCD swizzle so each A-panel (m0) lives on exactly one XCD L2
// with all 16 n-blocks co-resident; (b) chunk-summary scan (was scan_phase1)
// fused into the epilogue. FIXED vs r3: summaries composed per 16-row half
// (in-lane over r, ordered quad butterfly), then half0 o half1 — temporal
// order now respected; compose inputs are the bf16-ROUNDED (lc,lv) so the
// result is a pure reassociation of the old scan_phase1 numerics.
// ---------------------------------------------------------------------------
#define G1_NT (DIM / 64)        // 16 K-tiles
#define G2_NT (DIM_INNER / 64)  // 32 K-tiles

__global__ __launch_bounds__(512, 2) void gemm1_fused(
    const ushort_t* __restrict__ Xbf, const ushort_t* __restrict__ Wt,
    unsigned int* __restrict__ LCLV,
    float* __restrict__ Asum, float* __restrict__ Lend, int nbch) {
  __shared__ __align__(16) ushort_t lds[81920];   // 160 KB exactly

  const int tid = threadIdx.x;
  const int wv = tid >> 6;
  const int lane = tid & 63;
  const int wr = wv >> 2;           // 0..1 (M half)
  const int wc = wv & 3;            // 0..3 (N quarter)
  const int l15 = lane & 15;
  const int quad = lane >> 4;

  // ---- XCD-aware bijective swizzle: each XCD owns contiguous m-panels with
  // all 16 n-blocks. nwg divisible by 8 for all nb in {1,2,4}.
  const int nwg = gridDim.x * gridDim.y;        // 16 * (nrows/256)
  const int lin = blockIdx.y * gridDim.x + blockIdx.x;
  const int qchunk = nwg >> 3;
  const int wid = (lin & 7) * qchunk + (lin >> 3);
  const int n0 = (wid & 15) * 128;  // h-column base (g rows = +DIM_INNER in Wt)
  const int m0 = (wid >> 4) * 256;

  // ---- precomputed staging offsets (32-bit; exclude kt*64 which is affine)
  int aSrc[2][2], bSrc[2][2];   // [half][L]
  int dstE[2];
#pragma unroll
  for (int L = 0; L < 2; L++) {
    int e = L * 512 + tid;
    int row = e >> 3, slot = e & 7;
    int sw = (slot ^ (row & 7)) << 3;
    dstE[L] = e * 8;
#pragma unroll
    for (int half = 0; half < 2; half++) {
      aSrc[half][L] = (m0 + half * 128 + row) * DIM + sw;
      int br = half * 128 + row;
      int grow = n0 + ((br >> 6) << 5) + (br & 31) + ((br & 32) ? DIM_INNER : 0);
      bSrc[half][L] = grow * DIM + sw;
    }
  }

  auto stageA = [&](int kt, int half, int buf) {
#pragma unroll
    for (int L = 0; L < 2; L++)
      async_copy16(Xbf + aSrc[half][L] + kt * 64,
                   lds + buf * 16384 + half * 8192 + dstE[L]);
  };
  auto stageB = [&](int kt, int half, int buf) {
#pragma unroll
    for (int L = 0; L < 2; L++)
      async_copy16(Wt + bSrc[half][L] + kt * 64,
                   lds + 49152 + buf * 16384 + half * 8192 + dstE[L]);
  };

  // ---- precomputed ds_read bases (swz depends only on ks,quad,l15&7)
  const int swz0 = ((quad ^ (l15 & 7)) << 3);
  const int swz1 = (((4 | quad) ^ (l15 & 7)) << 3);
  const int aB0 = wr * 8192 + l15 * 64 + swz0;
  const int aB1 = wr * 8192 + l15 * 64 + swz1;
  const int bB0 = wc * 4096 + l15 * 64 + swz0;
  const int bB1 = wc * 4096 + l15 * 64 + swz1;

  auto readA = [&](int buf, int mf, int ks) -> bf16x8 {
    const ushort_t* p = lds + buf * 16384 + (ks ? aB1 : aB0) + mf * 1024;
    return __builtin_bit_cast(bf16x8, *(const short8_t*)p);
  };
  auto readB = [&](int buf, int nf, int ks) -> bf16x8 {
    const ushort_t* p = lds + 49152 + buf * 16384 + (ks ? bB1 : bB0) + nf * 1024;
    return __builtin_bit_cast(bf16x8, *(const short8_t*)p);
  };

  floatx4 acc[8][4];
#pragma unroll
  for (int i = 0; i < 8; i++)
#pragma unroll
    for (int j = 0; j < 4; j++) acc[i][j] = (floatx4){0.f, 0.f, 0.f, 0.f};

  bf16x8 aF[4][2], b0F[2][2], b1F[2][2];

  // 4 MFMA: aF[MA] x bX[0..1] -> acc[MC][J], acc[MC][J+1]
  auto mma4 = [&](auto MA, auto MC, auto J, bf16x8 (&bX)[2][2]) {
#pragma unroll
    for (int jj = 0; jj < 2; jj++)
#pragma unroll
      for (int ks = 0; ks < 2; ks++)
        acc[MC.v][J.v + jj] = __builtin_amdgcn_mfma_f32_16x16x32_bf16(
            aF[MA.v][ks], bX[jj][ks], acc[MC.v][J.v + jj], 0, 0, 0);
  };
  // 8 MFMA: aF[0..3] x bvec -> acc[0..3][J]
  auto mmaRow = [&](auto J, bf16x8 (&bvec)[2]) {
#pragma unroll
    for (int m = 0; m < 4; m++)
#pragma unroll
      for (int ks = 0; ks < 2; ks++)
        acc[m][J.v] = __builtin_amdgcn_mfma_f32_16x16x32_bf16(
            aF[m][ks], bvec[ks], acc[m][J.v], 0, 0, 0);
  };

  int bufA = 0, bufB = 0, bufAn = 2, bufBn = 1;

  auto tileBody = [&](int kb, int ka, auto STB, auto STA, auto VMALL) {
    // ---------- phase 0 : Q(mh0 x nh0); stage B(kb) half0
    aF[0][0] = readA(bufA, 0, 0); aF[0][1] = readA(bufA, 0, 1);
    b0F[0][0] = readB(bufB, 0, 0); b0F[0][1] = readB(bufB, 0, 1);
    b0F[1][0] = readB(bufB, 1, 0); b0F[1][1] = readB(bufB, 1, 1);
    SCHED0();
    aF[1][0] = readA(bufA, 1, 0); aF[1][1] = readA(bufA, 1, 1);
    SCHED0();
    aF[2][0] = readA(bufA, 2, 0); aF[2][1] = readA(bufA, 2, 1);
    SCHED0();
    aF[3][0] = readA(bufA, 3, 0); aF[3][1] = readA(bufA, 3, 1);
    SCHED0();
    if constexpr (STB.v) stageB(kb, 0, bufBn);
    SBAR();
    __builtin_amdgcn_s_setprio(1);
    LGKM_SB(6); mma4(IC<0>{}, IC<0>{}, IC<0>{}, b0F);
    LGKM_SB(4); mma4(IC<1>{}, IC<1>{}, IC<0>{}, b0F);
    LGKM_SB(2); mma4(IC<2>{}, IC<2>{}, IC<0>{}, b0F);
    LGKM_SB(0); mma4(IC<3>{}, IC<3>{}, IC<0>{}, b0F);
    __builtin_amdgcn_s_setprio(0);
    SBAR();

    // ---------- phase 1 : Q(mh0 x nh1); stage B(kb) half1
    b1F[0][0] = readB(bufB, 2, 0); b1F[0][1] = readB(bufB, 2, 1);
    SCHED0();
    b1F[1][0] = readB(bufB, 3, 0); b1F[1][1] = readB(bufB, 3, 1);
    SCHED0();
    if constexpr (STB.v) stageB(kb, 1, bufBn);
    SBAR();
    __builtin_amdgcn_s_setprio(1);
    LGKM_SB(2); mmaRow(IC<2>{}, b1F[0]);
    LGKM_SB(0); mmaRow(IC<3>{}, b1F[1]);
    __builtin_amdgcn_s_setprio(0);
    SBAR();

    // ---------- phase 2 : Q(mh1 x nh1); stage A(ka) half0
    aF[0][0] = readA(bufA, 4, 0); aF[0][1] = readA(bufA, 4, 1);
    SCHED0();
    aF[1][0] = readA(bufA, 5, 0); aF[1][1] = readA(bufA, 5, 1);
    SCHED0();
    aF[2][0] = readA(bufA, 6, 0); aF[2][1] = readA(bufA, 6, 1);
    SCHED0();
    aF[3][0] = readA(bufA, 7, 0); aF[3][1] = readA(bufA, 7, 1);
    SCHED0();
    if constexpr (STA.v) stageA(ka, 0, bufAn);
    SBAR();
    __builtin_amdgcn_s_setprio(1);
    LGKM_SB(6); mma4(IC<0>{}, IC<4>{}, IC<2>{}, b1F);
    LGKM_SB(4); mma4(IC<1>{}, IC<5>{}, IC<2>{}, b1F);
    LGKM_SB(2); mma4(IC<2>{}, IC<6>{}, IC<2>{}, b1F);
    LGKM_SB(0); mma4(IC<3>{}, IC<7>{}, IC<2>{}, b1F);
    __builtin_amdgcn_s_setprio(0);
    SBAR();

    // ---------- phase 3 : Q(mh1 x nh0); stage A(ka) half1; counted vmcnt
    if constexpr (STA.v) stageA(ka, 1, bufAn);
    SCHED0();
    if constexpr (STA.v) {
      asm volatile("s_waitcnt vmcnt(4)" ::: "memory");
    } else if constexpr (VMALL.v) {
      asm volatile("s_waitcnt vmcnt(0)" ::: "memory");
    }
    SBAR();
    __builtin_amdgcn_s_setprio(1);
    mma4(IC<0>{}, IC<4>{}, IC<0>{}, b0F);
    mma4(IC<1>{}, IC<5>{}, IC<0>{}, b0F);
    mma4(IC<2>{}, IC<6>{}, IC<0>{}, b0F);
    mma4(IC<3>{}, IC<7>{}, IC<0>{}, b0F);
    __builtin_amdgcn_s_setprio(0);
    SBAR();
  };

  // prologue: B(0), A(0), A(1); keep A(1)'s 4 loads in flight
  stageB(0, 0, 0); stageB(0, 1, 0);
  stageA(0, 0, 0); stageA(0, 1, 0);
  stageA(1, 0, 1); stageA(1, 1, 1);
  asm volatile("s_waitcnt vmcnt(4)" ::: "memory");
  SBAR();

  for (int u = 0; u < G1_NT - 2; u++) {
    tileBody(u + 1, u + 2, BC<true>{}, BC<true>{}, BC<false>{});
    bufA = (bufA == 2) ? 0 : bufA + 1;
    bufAn = (bufAn == 2) ? 0 : bufAn + 1;
    bufB ^= 1; bufBn ^= 1;
  }
  tileBody(G1_NT - 1, 0, BC<true>{}, BC<false>{}, BC<true>{});
  bufA = (bufA == 2) ? 0 : bufA + 1;
  bufB ^= 1;
  tileBody(0, 0, BC<false>{}, BC<false>{}, BC<false>{});

  // ---- epilogue: lc/lv pack + fused chunk summaries (was scan_phase1).
  // Chunk = 32 rows = mf pair {2c2, 2c2+1}. Row order within chunk:
  // mh*16 + quad*4 + r. Each 16-row half is composed separately (in-lane
  // over r -> ordered quad butterfly), then half0 o half1.
#pragma unroll
  for (int c2 = 0; c2 < 4; c2++) {
    float hA[2][2], hL[2][2];   // [mh][j]
#pragma unroll
    for (int mh = 0; mh < 2; mh++) {
      int mf = c2 * 2 + mh;
#pragma unroll
      for (int j = 0; j < 2; j++) {
        int col = n0 + wc * 32 + j * 16 + l15;
        float sA = 0.f, sL = -INFINITY;
#pragma unroll
        for (int r = 0; r < 4; r++) {
          int row = m0 + wr * 128 + mf * 16 + quad * 4 + r;
          float lc, lv;
          lclv_fast(acc[mf][j][r], acc[mf][j + 2][r], lc, lv);
          unsigned int pk = ((unsigned int)f2bf(lv) << 16) | (unsigned int)f2bf(lc);
          LCLV[(size_t)row * DIM_INNER + col] = pk;
          // compose with the ROUNDED values (matches old scan_phase1 input)
          float lcr = bflo2f(pk), lvr = bfhi2f(pk);
          sL = logaddexp_f(sL + lcr, lvr);
          sA += lcr;
        }
        // ordered butterfly across quad lanes (lane bits 4,5); compose is
        // non-commutative: lower-quad segment composes first.
        float A = sA, L = sL;
#pragma unroll
        for (int st = 16; st <= 32; st <<= 1) {
          float Ao = __shfl_xor(A, st, 64);
          float Lo = __shfl_xor(L, st, 64);
          bool upper = (lane & st) != 0;
          L = upper ? logaddexp_f(Lo + A, L) : logaddexp_f(L + Ao, Lo);
          A = A + Ao;
        }
        hA[mh][j] = A;
        hL[mh][j] = L;
      }
    }
#pragma unroll
    for (int j = 0; j < 2; j++) {
      float A = hA[0][j] + hA[1][j];
      float L = logaddexp_f(hL[0][j] + hA[1][j], hL[1][j]);
      if (quad == 0) {
        int cg = (m0 + wr * 128 + c2 * 32) >> 5;   // global chunk-row index
        int bz = cg >> 7;                          // NCHUNK = 128 chunks/seq
        int cs = cg & (NCHUNK - 1);
        int col = n0 + wc * 32 + j * 16 + l15;
        size_t sidx = (size_t)cs * nbch + (size_t)bz * DIM_INNER + col;
        Asum[sidx] = A;
        Lend[sidx] = L;
      }
    }
  }
}

// ---------------------------------------------------------------------------
// GEMM2 — same 256x256 template: out = H @ W_out, K = 2048 (32 tiles).
// grid = (DIM/256) x (rows/256) = 256 blocks -> exactly 1 per CU.
// ---------------------------------------------------------------------------
__global__ __launch_bounds__(512, 2) void gemm2(
    const ushort_t* __restrict__ Hbf, const ushort_t* __restrict__ Wot,
    float* __restrict__ OUT) {
  __shared__ __align__(16) ushort_t lds[81920];

  const int tid = threadIdx.x;
  const int wv = tid >> 6;
  const int lane = tid & 63;
  const int wr = wv >> 2;
  const int wc = wv & 3;
  const int l15 = lane & 15;
  const int quad = lane >> 4;
  const int n0 = blockIdx.x * 256;
  const int m0 = blockIdx.y * 256;

  int aSrc[2][2], bSrc[2][2];
  int dstE[2];
#pragma unroll
  for (int L = 0; L < 2; L++) {
    int e = L * 512 + tid;
    int row = e >> 3, slot = e & 7;
    int sw = (slot ^ (row & 7)) << 3;
    dstE[L] = e * 8;
#pragma unroll
    for (int half = 0; half < 2; half++) {
      aSrc[half][L] = (m0 + half * 128 + row) * DIM_INNER + sw;
      bSrc[half][L] = (n0 + half * 128 + row) * DIM_INNER + sw;
    }
  }

  auto stageA = [&](int kt, int half, int buf) {
#pragma unroll
    for (int L = 0; L < 2; L++)
      async_copy16(Hbf + aSrc[half][L] + kt * 64,
                   lds + buf * 16384 + half * 8192 + dstE[L]);
  };
  auto stageB = [&](int kt, int half, int buf) {
#pragma unroll
    for (int L = 0; L < 2; L++)
      async_copy16(Wot + bSrc[half][L] + kt * 64,
                   lds + 49152 + buf * 16384 + half * 8192 + dstE[L]);
  };

  const int swz0 = ((quad ^ (l15 & 7)) << 3);
  const int swz1 = (((4 | quad) ^ (l15 & 7)) << 3);
  const int aB0 = wr * 8192 + l15 * 64 + swz0;
  const int aB1 = wr * 8192 + l15 * 64 + swz1;
  const int bB0 = wc * 4096 + l15 * 64 + swz0;
  const int bB1 = wc * 4096 + l15 * 64 + swz1;

  auto readA = [&](int buf, int mf, int ks) -> bf16x8 {
    const ushort_t* p = lds + buf * 16384 + (ks ? aB1 : aB0) + mf * 1024;
    return __builtin_bit_cast(bf16x8, *(const short8_t*)p);
  };
  auto readB = [&](int buf, int nf, int ks) -> bf16x8 {
    const ushort_t* p = lds + 49152 + buf * 16384 + (ks ? bB1 : bB0) + nf * 1024;
    return __builtin_bit_cast(bf16x8, *(const short8_t*)p);
  };

  floatx4 acc[8][4];
#pragma unroll
  for (int i = 0; i < 8; i++)
#pragma unroll
    for (int j = 0; j < 4; j++) acc[i][j] = (floatx4){0.f, 0.f, 0.f, 0.f};

  bf16x8 aF[4][2], b0F[2][2], b1F[2][2];

  auto mma4 = [&](auto MA, auto MC, auto J, bf16x8 (&bX)[2][2]) {
#pragma unroll
    for (int jj = 0; jj < 2; jj++)
#pragma unroll
      for (int ks = 0; ks < 2; ks++)
        acc[MC.v][J.v + jj] = __builtin_amdgcn_mfma_f32_16x16x32_bf16(
            aF[MA.v][ks], bX[jj][ks], acc[MC.v][J.v + jj], 0, 0, 0);
  };
  auto mmaRow = [&](auto J, bf16x8 (&bvec)[2]) {
#pragma unroll
    for (int m = 0; m < 4; m++)
#pragma unroll
      for (int ks = 0; ks < 2; ks++)
        acc[m][J.v] = __builtin_amdgcn_mfma_f32_16x16x32_bf16(
            aF[m][ks], bvec[ks], acc[m][J.v], 0, 0, 0);
  };

  int bufA = 0, bufB = 0, bufAn = 2, bufBn = 1;

  auto tileBody = [&](int kb, int ka, auto STB, auto STA, auto VMALL) {
    aF[0][0] = readA(bufA, 0, 0); aF[0][1] = readA(bufA, 0, 1);
    b0F[0][0] = readB(bufB, 0, 0); b0F[0][1] = readB(bufB, 0, 1);
    b0F[1][0] = readB(bufB, 1, 0); b0F[1][1] = readB(bufB, 1, 1);
    SCHED0();
    aF[1][0] = readA(bufA, 1, 0); aF[1][1] = readA(bufA, 1, 1);
    SCHED0();
    aF[2][0] = readA(bufA, 2, 0); aF[2][1] = readA(bufA, 2, 1);
    SCHED0();
    aF[3][0] = readA(bufA, 3, 0); aF[3][1] = readA(bufA, 3, 1);
    SCHED0();
    if constexpr (STB.v) stageB(kb, 0, bufBn);
    SBAR();
    __builtin_amdgcn_s_setprio(1);
    LGKM_SB(6); mma4(IC<0>{}, IC<0>{}, IC<0>{}, b0F);
    LGKM_SB(4); mma4(IC<1>{}, IC<1>{}, IC<0>{}, b0F);
    LGKM_SB(2); mma4(IC<2>{}, IC<2>{}, IC<0>{}, b0F);
    LGKM_SB(0); mma4(IC<3>{}, IC<3>{}, IC<0>{}, b0F);
    __builtin_amdgcn_s_setprio(0);
    SBAR();

    b1F[0][0] = readB(bufB, 2, 0); b1F[0][1] = readB(bufB, 2, 1);
    SCHED0();
    b1F[1][0] = readB(bufB, 3, 0); b1F[1][1] = readB(bufB, 3, 1);
    SCHED0();
    if constexpr (STB.v) stageB(kb, 1, bufBn);
    SBAR();
    __builtin_amdgcn_s_setprio(1);
    LGKM_SB(2); mmaRow(IC<2>{}, b1F[0]);
    LGKM_SB(0); mmaRow(IC<3>{}, b1F[1]);
    __builtin_amdgcn_s_setprio(0);
    SBAR();

    aF[0][0] = readA(bufA, 4, 0); aF[0][1] = readA(bufA, 4, 1);
    SCHED0();
    aF[1][0] = readA(bufA, 5, 0); aF[1][1] = readA(bufA, 5, 1);
    SCHED0();
    aF[2][0] = readA(bufA, 6, 0); aF[2][1] = readA(bufA, 6, 1);
    SCHED0();
    aF[3][0] = readA(bufA, 7, 0); aF[3][1] = readA(bufA, 7, 1);
    SCHED0();
    if constexpr (STA.v) stageA(ka, 0, bufAn);
    SBAR();
    __builtin_amdgcn_s_setprio(1);
    LGKM_SB(6); mma4(IC<0>{}, IC<4>{}, IC<2>{}, b1F);
    LGKM_SB(4); mma4(IC<1>{}, IC<5>{}, IC<2>{}, b1F);
    LGKM_SB(2); mma4(IC<2>{}, IC<6>{}, IC<2>{}, b1F);
    LGKM_SB(0); mma4(IC<3>{}, IC<7>{}, IC<2>{}, b1F);
    __builtin_amdgcn_s_setprio(0);
    SBAR();

    if constexpr (STA.v) stageA(ka, 1, bufAn);
    SCHED0();
    if constexpr (STA.v) {
      asm volatile("s_waitcnt vmcnt(4)" ::: "memory");
    } else if constexpr (VMALL.v) {
      asm volatile("s_waitcnt vmcnt(0)" ::: "memory");
    }
    SBAR();
    __builtin_amdgcn_s_setprio(1);
    mma4(IC<0>{}, IC<4>{}, IC<0>{}, b0F);
    mma4(IC<1>{}, IC<5>{}, IC<0>{}, b0F);
    mma4(IC<2>{}, IC<6>{}, IC<0>{}, b0F);
    mma4(IC<3>{}, IC<7>{}, IC<0>{}, b0F);
    __builtin_amdgcn_s_setprio(0);
    SBAR();
  };

  stageB(0, 0, 0); stageB(0, 1, 0);
  stageA(0, 0, 0); stageA(0, 1, 0);
  stageA(1, 0, 1); stageA(1, 1, 1);
  asm volatile("s_waitcnt vmcnt(4)" ::: "memory");
  SBAR();

  for (int u = 0; u < G2_NT - 2; u++) {
    tileBody(u + 1, u + 2, BC<true>{}, BC<true>{}, BC<false>{});
    bufA = (bufA == 2) ? 0 : bufA + 1;
    bufAn = (bufAn == 2) ? 0 : bufAn + 1;
    bufB ^= 1; bufBn ^= 1;
  }
  tileBody(G2_NT - 1, 0, BC<true>{}, BC<false>{}, BC<true>{});
  bufA = (bufA == 2) ? 0 : bufA + 1;
  bufB ^= 1;
  tileBody(0, 0, BC<false>{}, BC<false>{}, BC<false>{});

#pragma unroll
  for (int mf = 0; mf < 8; mf++)
#pragma unroll
    for (int j = 0; j < 4; j++) {
      int col = n0 + wc * 64 + (j >> 1) * 32 + (j & 1) * 16 + l15;
#pragma unroll
      for (int r = 0; r < 4; r++) {
        int row = m0 + wr * 128 + mf * 16 + quad * 4 + r;
        OUT[(size_t)row * DIM + col] = acc[mf][j][r];
      }
    }
}

// ---------------------------------------------------------------------------
// Chunk-prefix + rescan (scan_phase1 now fused into gemm1's epilogue)
// ---------------------------------------------------------------------------

// In-place: Asum[c][ch] -> P[c][ch] (prefix BEFORE chunk c)
__global__ __launch_bounds__(256) void scan_phase2(
    float* Asum, const float* __restrict__ Lend, int nbch) {
  int ch = blockIdx.x * 256 + threadIdx.x;
  float p = -INFINITY;
  for (int c = 0; c < NCHUNK; c++) {
    float a = Asum[(size_t)c * nbch + ch];
    float le = Lend[(size_t)c * nbch + ch];
    Asum[(size_t)c * nbch + ch] = p;
    p = logaddexp_f(a + p, le);
  }
}

// Rescan with real prefix; write h = exp(log_h) as bf16 into H (8B/lane).
__global__ __launch_bounds__(256) void scan_phase3(
    const unsigned int* __restrict__ LCLV, const float* __restrict__ P,
    ushort_t* __restrict__ H, int nbch) {
  const int EQ = DIM_INNER / 4;
  int tid = blockIdx.x * 256 + threadIdx.x;
  int ep = tid % EQ;
  int tmp = tid / EQ;
  int c = tmp % NCHUNK;
  int bz = tmp / NCHUNK;
  size_t base4 = ((size_t)bz * SEQ + (size_t)c * CHUNK) * EQ + ep;
  const uint4_t* L4 = (const uint4_t*)LCLV;
  u16x4* H4 = (u16x4*)H;

  size_t pidx = ((size_t)c * nbch + (size_t)bz * DIM_INNER) / 4 + ep;
  float4_t logh = ((const float4_t*)P)[pidx];
#pragma unroll 4
  for (int t = 0; t < CHUNK; t++) {
    uint4_t u = L4[base4 + (size_t)t * EQ];
    u16x4 hv;
#pragma unroll
    for (int k = 0; k < 4; k++) {
      float lc = bflo2f(u[k]), lv = bfhi2f(u[k]);
      logh[k] = logaddexp_f(lc + logh[k], lv);
      hv[k] = f2bf(__expf(logh[k]));
    }
    H4[base4 + (size_t)t * EQ] = hv;
  }
}

extern "C" void kernel_launch(void* const* d_in, const int* in_sizes, int n_in,
                              void* d_out, int out_size, void* d_ws, size_t ws_size,
                              hipStream_t stream) {
  const float* X = (const float*)d_in[0];     // [4,4096,1024]
  const float* Whg = (const float*)d_in[1];   // [1024,4096]
  const float* Wout = (const float*)d_in[2];  // [2048,1024]
  float* out = (float*)d_out;                 // [4,4096,1024] fp32

  ushort_t* Xbf = (ushort_t*)d_ws;
  ushort_t* Whg_t = Xbf + (size_t)MTOT * DIM;                   // [4096][1024]
  ushort_t* Wout_t = Whg_t + (size_t)(2 * DIM_INNER) * DIM;     // [1024][2048]
  char* pp = (char*)(Wout_t + (size_t)DIM * DIM_INNER);

  const size_t fixed_bytes = (size_t)MTOT * DIM * 2 +
                             (size_t)2 * DIM_INNER * DIM * 2 +
                             (size_t)DIM * DIM_INNER * 2;
  // per batch: LCLV 4B + H 2B per elem + 2 summaries
  const size_t per_batch = (size_t)SEQ * DIM_INNER * 4 +
                           (size_t)SEQ * DIM_INNER * 2 +
                           2 * (size_t)DIM_INNER * NCHUNK * 4;
  int nb = 4;
  while (nb > 1 && fixed_bytes + (size_t)nb * per_batch > ws_size) nb >>= 1;
  const int npass = BATCH / nb;

  convert_f32_bf16<<<(MTOT * DIM / 4) / 256, 256, 0, stream>>>(X, Xbf);
  transpose_f32_bf16<<<dim3(2 * DIM_INNER / 32, DIM / 32), 256, 0, stream>>>(
      Whg, Whg_t, DIM, 2 * DIM_INNER);
  transpose_f32_bf16<<<dim3(DIM / 32, DIM_INNER / 32), 256, 0, stream>>>(
      Wout, Wout_t, DIM_INNER, DIM);

  for (int pass = 0; pass < npass; pass++) {
    const int b0 = pass * nb;
    const int nrows = nb * SEQ;
    const int nbch = nb * DIM_INNER;

    unsigned int* LCLV = (unsigned int*)pp;
    ushort_t* Hbf = (ushort_t*)(LCLV + (size_t)nb * SEQ * DIM_INNER);
    float* Asum = (float*)(Hbf + (size_t)nb * SEQ * DIM_INNER);
    float* Lend = Asum + (size_t)nb * DIM_INNER * NCHUNK;

    gemm1_fused<<<dim3(DIM_INNER / 128, nrows / 256), 512, 0, stream>>>(
        Xbf + (size_t)b0 * SEQ * DIM, Whg_t, LCLV, Asum, Lend, nbch);
    scan_phase2<<<nbch / 256, 256, 0, stream>>>(Asum, Lend, nbch);
    scan_phase3<<<(nbch / 4 * NCHUNK) / 256, 256, 0, stream>>>(LCLV, Asum, Hbf, nbch);
    gemm2<<<dim3(DIM / 256, nrows / 256), 512, 0, stream>>>(
        Hbf, Wout_t, out + (size_t)b0 * SEQ * DIM);
  }
}

// Round 5
// 451.478 us; speedup vs baseline: 1.0008x; 1.0008x over previous
//
#include <hip/hip_runtime.h>
#include <cmath>

#define DIM 1024
#define DIM_INNER 2048
#define BATCH 4
#define SEQ 4096
#define MTOT (BATCH * SEQ)
#define CHUNK 32
#define NCHUNK (SEQ / CHUNK)        // 128 chunks per sequence

typedef __bf16 bf16x8 __attribute__((ext_vector_type(8)));
typedef short short8_t __attribute__((ext_vector_type(8)));
typedef float floatx4 __attribute__((ext_vector_type(4)));
typedef unsigned short u16x4 __attribute__((ext_vector_type(4)));
typedef unsigned int uint4_t __attribute__((ext_vector_type(4)));
typedef float float4_t __attribute__((ext_vector_type(4)));
typedef unsigned short ushort_t;

template <int N> struct IC { static constexpr int v = N; };
template <bool B> struct BC { static constexpr bool v = B; };

#define LGKM_SB(n) do { asm volatile("s_waitcnt lgkmcnt(" #n ")" ::: "memory"); \
                        __builtin_amdgcn_sched_barrier(0); } while (0)
#define SCHED0() __builtin_amdgcn_sched_barrier(0)
#define SBAR() __builtin_amdgcn_s_barrier()
#define PRIO1() __builtin_amdgcn_s_setprio(1)
#define PRIO0() __builtin_amdgcn_s_setprio(0)

__device__ __forceinline__ unsigned short f2bf(float f) {
  unsigned int u = __builtin_bit_cast(unsigned int, f);
  u += 0x7fffu + ((u >> 16) & 1u);   // round-to-nearest-even
  return (unsigned short)(u >> 16);
}
__device__ __forceinline__ float bflo2f(unsigned int u) {
  return __builtin_bit_cast(float, u << 16);
}
__device__ __forceinline__ float bfhi2f(unsigned int u) {
  return __builtin_bit_cast(float, u & 0xffff0000u);
}

// Fast (native v_exp/v_log) log-space terms from (h, g):
//   lc = -softplus(g) ;  lv = -softplus(-g) + log_g(h) = g + lc + log_g(h)
__device__ __forceinline__ void lclv_fast(float h, float g, float& lc, float& lv) {
  float eg = __expf(-fabsf(g));
  float sp = fmaxf(g, 0.f) + __logf(1.f + eg);
  lc = -sp;
  float eh = __expf(h);
  float t  = (h >= 0.f) ? (h + 0.5f) : (1.f + eh);
  float lt = __logf(t);
  float lg = (h >= 0.f) ? lt : (h - lt);
  lv = g + lc + lg;
}
// a may be -inf; b finite
__device__ __forceinline__ float logaddexp_f(float a, float b) {
  float m = fmaxf(a, b);
  return m + __logf(1.f + __expf(-fabsf(a - b)));
}

// async 16B/lane global->LDS; dest = wave-uniform base + lane*16
__device__ __forceinline__ void async_copy16(const ushort_t* g, ushort_t* l) {
  __builtin_amdgcn_global_load_lds(
      (const __attribute__((address_space(1))) void*)g,
      (__attribute__((address_space(3))) void*)l, 16, 0, 0);
}

// ---------------------------------------------------------------------------
// One-time input conversions
// ---------------------------------------------------------------------------
__global__ __launch_bounds__(256) void convert_f32_bf16(
    const float* __restrict__ src, ushort_t* __restrict__ dst) {
  int i = blockIdx.x * 256 + threadIdx.x;   // one float4 per thread
  float4 v = ((const float4*)src)[i];
  u16x4 o = {f2bf(v.x), f2bf(v.y), f2bf(v.z), f2bf(v.w)};
  ((u16x4*)dst)[i] = o;
}

// dst[n][k] = bf16(src[k][n]); src is [K][N] fp32
__global__ __launch_bounds__(256) void transpose_f32_bf16(
    const float* __restrict__ src, ushort_t* __restrict__ dst, int K, int N) {
  __shared__ float tile[32][33];
  int tx = threadIdx.x & 31, ty = threadIdx.x >> 5;   // 32 x 8
  int n0 = blockIdx.x * 32, k0 = blockIdx.y * 32;
#pragma unroll
  for (int i = 0; i < 4; i++) {
    int k = ty + i * 8;
    tile[k][tx] = src[(size_t)(k0 + k) * N + n0 + tx];
  }
  __syncthreads();
#pragma unroll
  for (int i = 0; i < 4; i++) {
    int r = ty + i * 8;
    dst[(size_t)(n0 + r) * K + k0 + tx] = f2bf(tile[tx][r]);
  }
}

// ---------------------------------------------------------------------------
// Shared GEMM skeleton: 256-row x 256-B-row tile, 8 waves, BK=64.
// m201-faithful: 2 K-tiles/iteration, STATIC double buffers (A0/A1/B0/B1 at
// fixed LDS offsets, 128 KB), one half-tile stage per phase placed strictly
// after the target buffer's last read (barrier-separated), counted vmcnt(4)
// @ph3 and vmcnt(8) @ph7 (never 0 in main loop), and per phase a single
// lgkmcnt(0) followed by an UNBROKEN 16-MFMA block.
// ---------------------------------------------------------------------------
#define G1_NT (DIM / 64)        // 16 K-tiles
#define G2_NT (DIM_INNER / 64)  // 32 K-tiles
// LDS offsets (ushort units): A bufs 32 KB each, B bufs 32 KB each
#define A0OFF 0
#define A1OFF 16384
#define B0OFF 32768
#define B1OFF 49152

__global__ __launch_bounds__(512, 2) void gemm1_fused(
    const ushort_t* __restrict__ Xbf, const ushort_t* __restrict__ Wt,
    unsigned int* __restrict__ LCLV,
    float* __restrict__ Asum, float* __restrict__ Lend, int nbch) {
  __shared__ __align__(16) ushort_t lds[65536];   // 128 KB

  const int tid = threadIdx.x;
  const int lane = tid & 63;
  const int wv = tid >> 6;
  const int wr = wv >> 2;           // 0..1 (M half)
  const int wc = wv & 3;            // 0..3 (N quarter)
  const int l15 = lane & 15;
  const int quad = lane >> 4;
  const int n0 = blockIdx.x * 128;  // h-column base (g rows = +DIM_INNER in Wt)
  const int m0 = blockIdx.y * 256;

  // ---- precomputed staging offsets (32-bit; kt*64 added per call, affine)
  int aSrc[2][2], bSrc[2][2];   // [half][L]
  int dstE[2];
#pragma unroll
  for (int L = 0; L < 2; L++) {
    int e = L * 512 + tid;
    int row = e >> 3, slot = e & 7;
    int sw = (slot ^ (row & 7)) << 3;
    dstE[L] = e * 8;
#pragma unroll
    for (int half = 0; half < 2; half++) {
      aSrc[half][L] = (m0 + half * 128 + row) * DIM + sw;
      int br = half * 128 + row;
      int grow = n0 + ((br >> 6) << 5) + (br & 31) + ((br & 32) ? DIM_INNER : 0);
      bSrc[half][L] = grow * DIM + sw;
    }
  }

  auto stA = [&](int kt, int half, auto AO) {
#pragma unroll
    for (int L = 0; L < 2; L++)
      async_copy16(Xbf + aSrc[half][L] + kt * 64,
                   lds + AO.v + half * 8192 + dstE[L]);
  };
  auto stB = [&](int kt, int half, auto BO) {
#pragma unroll
    for (int L = 0; L < 2; L++)
      async_copy16(Wt + bSrc[half][L] + kt * 64,
                   lds + BO.v + half * 8192 + dstE[L]);
  };

  // ---- ds_read bases (XOR swizzle; row&7 == l15&7 for all our rows)
  const int swz0 = ((quad ^ (l15 & 7)) << 3);
  const int swz1 = (((4 | quad) ^ (l15 & 7)) << 3);
  const int aB0 = wr * 8192 + l15 * 64 + swz0;
  const int aB1 = wr * 8192 + l15 * 64 + swz1;
  const int bB0 = wc * 4096 + l15 * 64 + swz0;
  const int bB1 = wc * 4096 + l15 * 64 + swz1;

  floatx4 acc[8][4];
#pragma unroll
  for (int i = 0; i < 8; i++)
#pragma unroll
    for (int j = 0; j < 4; j++) acc[i][j] = (floatx4){0.f, 0.f, 0.f, 0.f};

  bf16x8 aF[4][2], b0F[2][2], b1F[2][2];

  auto rdA4 = [&](auto AO, int mb) {
#pragma unroll
    for (int m = 0; m < 4; m++) {
      aF[m][0] = __builtin_bit_cast(bf16x8,
          *(const short8_t*)(lds + AO.v + aB0 + (mb + m) * 1024));
      aF[m][1] = __builtin_bit_cast(bf16x8,
          *(const short8_t*)(lds + AO.v + aB1 + (mb + m) * 1024));
    }
  };
  auto rdB2 = [&](auto BO, int nb, bf16x8 (&bX)[2][2]) {
#pragma unroll
    for (int n = 0; n < 2; n++) {
      bX[n][0] = __builtin_bit_cast(bf16x8,
          *(const short8_t*)(lds + BO.v + bB0 + (nb + n) * 1024));
      bX[n][1] = __builtin_bit_cast(bf16x8,
          *(const short8_t*)(lds + BO.v + bB1 + (nb + n) * 1024));
    }
  };
  // unbroken 16-MFMA block: acc[MB..MB+3][JB..JB+1]
  auto mmaQ = [&](auto MB, auto JB, bf16x8 (&bX)[2][2]) {
#pragma unroll
    for (int m = 0; m < 4; m++)
#pragma unroll
      for (int jj = 0; jj < 2; jj++)
#pragma unroll
        for (int ks = 0; ks < 2; ks++)
          acc[MB.v + m][JB.v + jj] = __builtin_amdgcn_mfma_f32_16x16x32_bf16(
              aF[m][ks], bX[jj][ks], acc[MB.v + m][JB.v + jj], 0, 0, 0);
  };

  // ---- 2-K-tile iteration: T0 on A0/B0, T1 on A1/B1; stages tiles k2,k2+1
  auto pairBody = [&](int k2, auto STG) {
    // ph0 : T0 Q(m0-3 x nh0)
    rdA4(IC<A0OFF>{}, 0); rdB2(IC<B0OFF>{}, 0, b0F);
    SCHED0();
    SBAR(); LGKM_SB(0);
    PRIO1(); mmaQ(IC<0>{}, IC<0>{}, b0F); PRIO0();
    SBAR();
    // ph1 : T0 Q(m0-3 x nh1)
    rdB2(IC<B0OFF>{}, 2, b1F);
    SCHED0();
    SBAR(); LGKM_SB(0);
    PRIO1(); mmaQ(IC<0>{}, IC<2>{}, b1F); PRIO0();
    SBAR();
    // ph2 : T0 Q(m4-7 x nh1); stage B(k2)h0 -> B0 (B0 last read ph1)
    rdA4(IC<A0OFF>{}, 4);
    SCHED0();
    if constexpr (STG.v) stB(k2, 0, IC<B0OFF>{});
    SBAR(); LGKM_SB(0);
    PRIO1(); mmaQ(IC<4>{}, IC<2>{}, b1F); PRIO0();
    SBAR();
    // ph3 : T0 Q(m4-7 x nh0); stage B(k2)h1; vmcnt(4) drains prev-iter T1
    if constexpr (STG.v) {
      stB(k2, 1, IC<B0OFF>{});
      asm volatile("s_waitcnt vmcnt(4)" ::: "memory");
    } else {
      asm volatile("s_waitcnt vmcnt(0)" ::: "memory");
    }
    SBAR();
    PRIO1(); mmaQ(IC<4>{}, IC<0>{}, b0F); PRIO0();
    SBAR();
    // ph4 : T1 Q(m0-3 x nh0); stage A(k2)h0 -> A0 (A0 last read ph2)
    rdA4(IC<A1OFF>{}, 0); rdB2(IC<B1OFF>{}, 0, b0F);
    SCHED0();
    if constexpr (STG.v) stA(k2, 0, IC<A0OFF>{});
    SBAR(); LGKM_SB(0);
    PRIO1(); mmaQ(IC<0>{}, IC<0>{}, b0F); PRIO0();
    SBAR();
    // ph5 : T1 Q(m0-3 x nh1); stage A(k2)h1
    rdB2(IC<B1OFF>{}, 2, b1F);
    SCHED0();
    if constexpr (STG.v) stA(k2, 1, IC<A0OFF>{});
    SBAR(); LGKM_SB(0);
    PRIO1(); mmaQ(IC<0>{}, IC<2>{}, b1F); PRIO0();
    SBAR();
    // ph6 : T1 Q(m4-7 x nh1); stage B(k2+1)h0 -> B1 (B1 last read ph5)
    rdA4(IC<A1OFF>{}, 4);
    SCHED0();
    if constexpr (STG.v) stB(k2 + 1, 0, IC<B1OFF>{});
    SBAR(); LGKM_SB(0);
    PRIO1(); mmaQ(IC<4>{}, IC<2>{}, b1F); PRIO0();
    SBAR();
    // ph7 : T1 Q(m4-7 x nh0); stage B(k2+1)h1 + A(k2+1)h0,h1 -> A1;
    //       vmcnt(8) drains B(k2),A(k2) for next-iter ph0
    if constexpr (STG.v) {
      stB(k2 + 1, 1, IC<B1OFF>{});
      stA(k2 + 1, 0, IC<A1OFF>{});
      stA(k2 + 1, 1, IC<A1OFF>{});
      asm volatile("s_waitcnt vmcnt(8)" ::: "memory");
    }
    SBAR();
    PRIO1(); mmaQ(IC<4>{}, IC<0>{}, b0F); PRIO0();
    SBAR();
  };

  // prologue: tiles 0 -> A0/B0, 1 -> A1/B1; drain tile 0
  stA(0, 0, IC<A0OFF>{}); stA(0, 1, IC<A0OFF>{});
  stB(0, 0, IC<B0OFF>{}); stB(0, 1, IC<B0OFF>{});
  stA(1, 0, IC<A1OFF>{}); stA(1, 1, IC<A1OFF>{});
  stB(1, 0, IC<B1OFF>{}); stB(1, 1, IC<B1OFF>{});
  asm volatile("s_waitcnt vmcnt(8)" ::: "memory");
  SBAR();

  for (int it = 0; it < G1_NT / 2 - 1; ++it)
    pairBody(2 * it + 2, BC<true>{});
  pairBody(0, BC<false>{});   // tail: tiles NT-2, NT-1 already resident

  // ---- epilogue: lc/lv pack + fused chunk summaries (was scan_phase1).
  // Chunk = 32 rows = mf pair {2c2, 2c2+1}; row order mh*16 + quad*4 + r.
  // Per 16-row half: in-lane compose over r, ordered quad butterfly; then
  // half0 o half1. Compose on fp32 (pre-rounding) values.
#pragma unroll
  for (int c2 = 0; c2 < 4; c2++) {
    float hA[2][2], hL[2][2];   // [mh][j]
#pragma unroll
    for (int mh = 0; mh < 2; mh++) {
      int mf = c2 * 2 + mh;
#pragma unroll
      for (int j = 0; j < 2; j++) {
        int col = n0 + wc * 32 + j * 16 + l15;
        float sA = 0.f, sL = -INFINITY;
#pragma unroll
        for (int r = 0; r < 4; r++) {
          int row = m0 + wr * 128 + mf * 16 + quad * 4 + r;
          float lc, lv;
          lclv_fast(acc[mf][j][r], acc[mf][j + 2][r], lc, lv);
          unsigned int pk = ((unsigned int)f2bf(lv) << 16) | (unsigned int)f2bf(lc);
          LCLV[(size_t)row * DIM_INNER + col] = pk;
          sL = logaddexp_f(sL + lc, lv);
          sA += lc;
        }
        // ordered butterfly across quad lanes (bits 4,5): lower-quad first
        float A = sA, L = sL;
#pragma unroll
        for (int st = 16; st <= 32; st <<= 1) {
          float Ao = __shfl_xor(A, st, 64);
          float Lo = __shfl_xor(L, st, 64);
          bool upper = (lane & st) != 0;
          L = upper ? logaddexp_f(Lo + A, L) : logaddexp_f(L + Ao, Lo);
          A = A + Ao;
        }
        hA[mh][j] = A;
        hL[mh][j] = L;
      }
    }
#pragma unroll
    for (int j = 0; j < 2; j++) {
      float A = hA[0][j] + hA[1][j];
      float L = logaddexp_f(hL[0][j] + hA[1][j], hL[1][j]);
      if (quad == 0) {
        int cg = (m0 + wr * 128 + c2 * 32) >> 5;   // global chunk-row index
        int bz = cg >> 7;                          // NCHUNK = 128 chunks/seq
        int cs = cg & (NCHUNK - 1);
        int col = n0 + wc * 32 + j * 16 + l15;
        size_t sidx = (size_t)cs * nbch + (size_t)bz * DIM_INNER + col;
        Asum[sidx] = A;
        Lend[sidx] = L;
      }
    }
  }
}

// ---------------------------------------------------------------------------
// GEMM2 — same skeleton: out = H @ W_out, K = 2048 (32 tiles).
// grid = (DIM/256) x (rows/256) = 256 blocks -> 1 per CU.
// ---------------------------------------------------------------------------
__global__ __launch_bounds__(512, 2) void gemm2(
    const ushort_t* __restrict__ Hbf, const ushort_t* __restrict__ Wot,
    float* __restrict__ OUT) {
  __shared__ __align__(16) ushort_t lds[65536];

  const int tid = threadIdx.x;
  const int lane = tid & 63;
  const int wv = tid >> 6;
  const int wr = wv >> 2;
  const int wc = wv & 3;
  const int l15 = lane & 15;
  const int quad = lane >> 4;
  const int n0 = blockIdx.x * 256;
  const int m0 = blockIdx.y * 256;

  int aSrc[2][2], bSrc[2][2];
  int dstE[2];
#pragma unroll
  for (int L = 0; L < 2; L++) {
    int e = L * 512 + tid;
    int row = e >> 3, slot = e & 7;
    int sw = (slot ^ (row & 7)) << 3;
    dstE[L] = e * 8;
#pragma unroll
    for (int half = 0; half < 2; half++) {
      aSrc[half][L] = (m0 + half * 128 + row) * DIM_INNER + sw;
      bSrc[half][L] = (n0 + half * 128 + row) * DIM_INNER + sw;
    }
  }

  auto stA = [&](int kt, int half, auto AO) {
#pragma unroll
    for (int L = 0; L < 2; L++)
      async_copy16(Hbf + aSrc[half][L] + kt * 64,
                   lds + AO.v + half * 8192 + dstE[L]);
  };
  auto stB = [&](int kt, int half, auto BO) {
#pragma unroll
    for (int L = 0; L < 2; L++)
      async_copy16(Wot + bSrc[half][L] + kt * 64,
                   lds + BO.v + half * 8192 + dstE[L]);
  };

  const int swz0 = ((quad ^ (l15 & 7)) << 3);
  const int swz1 = (((4 | quad) ^ (l15 & 7)) << 3);
  const int aB0 = wr * 8192 + l15 * 64 + swz0;
  const int aB1 = wr * 8192 + l15 * 64 + swz1;
  const int bB0 = wc * 4096 + l15 * 64 + swz0;
  const int bB1 = wc * 4096 + l15 * 64 + swz1;

  floatx4 acc[8][4];
#pragma unroll
  for (int i = 0; i < 8; i++)
#pragma unroll
    for (int j = 0; j < 4; j++) acc[i][j] = (floatx4){0.f, 0.f, 0.f, 0.f};

  bf16x8 aF[4][2], b0F[2][2], b1F[2][2];

  auto rdA4 = [&](auto AO, int mb) {
#pragma unroll
    for (int m = 0; m < 4; m++) {
      aF[m][0] = __builtin_bit_cast(bf16x8,
          *(const short8_t*)(lds + AO.v + aB0 + (mb + m) * 1024));
      aF[m][1] = __builtin_bit_cast(bf16x8,
          *(const short8_t*)(lds + AO.v + aB1 + (mb + m) * 1024));
    }
  };
  auto rdB2 = [&](auto BO, int nb, bf16x8 (&bX)[2][2]) {
#pragma unroll
    for (int n = 0; n < 2; n++) {
      bX[n][0] = __builtin_bit_cast(bf16x8,
          *(const short8_t*)(lds + BO.v + bB0 + (nb + n) * 1024));
      bX[n][1] = __builtin_bit_cast(bf16x8,
          *(const short8_t*)(lds + BO.v + bB1 + (nb + n) * 1024));
    }
  };
  auto mmaQ = [&](auto MB, auto JB, bf16x8 (&bX)[2][2]) {
#pragma unroll
    for (int m = 0; m < 4; m++)
#pragma unroll
      for (int jj = 0; jj < 2; jj++)
#pragma unroll
        for (int ks = 0; ks < 2; ks++)
          acc[MB.v + m][JB.v + jj] = __builtin_amdgcn_mfma_f32_16x16x32_bf16(
              aF[m][ks], bX[jj][ks], acc[MB.v + m][JB.v + jj], 0, 0, 0);
  };

  auto pairBody = [&](int k2, auto STG) {
    rdA4(IC<A0OFF>{}, 0); rdB2(IC<B0OFF>{}, 0, b0F);
    SCHED0();
    SBAR(); LGKM_SB(0);
    PRIO1(); mmaQ(IC<0>{}, IC<0>{}, b0F); PRIO0();
    SBAR();
    rdB2(IC<B0OFF>{}, 2, b1F);
    SCHED0();
    SBAR(); LGKM_SB(0);
    PRIO1(); mmaQ(IC<0>{}, IC<2>{}, b1F); PRIO0();
    SBAR();
    rdA4(IC<A0OFF>{}, 4);
    SCHED0();
    if constexpr (STG.v) stB(k2, 0, IC<B0OFF>{});
    SBAR(); LGKM_SB(0);
    PRIO1(); mmaQ(IC<4>{}, IC<2>{}, b1F); PRIO0();
    SBAR();
    if constexpr (STG.v) {
      stB(k2, 1, IC<B0OFF>{});
      asm volatile("s_waitcnt vmcnt(4)" ::: "memory");
    } else {
      asm volatile("s_waitcnt vmcnt(0)" ::: "memory");
    }
    SBAR();
    PRIO1(); mmaQ(IC<4>{}, IC<0>{}, b0F); PRIO0();
    SBAR();
    rdA4(IC<A1OFF>{}, 0); rdB2(IC<B1OFF>{}, 0, b0F);
    SCHED0();
    if constexpr (STG.v) stA(k2, 0, IC<A0OFF>{});
    SBAR(); LGKM_SB(0);
    PRIO1(); mmaQ(IC<0>{}, IC<0>{}, b0F); PRIO0();
    SBAR();
    rdB2(IC<B1OFF>{}, 2, b1F);
    SCHED0();
    if constexpr (STG.v) stA(k2, 1, IC<A0OFF>{});
    SBAR(); LGKM_SB(0);
    PRIO1(); mmaQ(IC<0>{}, IC<2>{}, b1F); PRIO0();
    SBAR();
    rdA4(IC<A1OFF>{}, 4);
    SCHED0();
    if constexpr (STG.v) stB(k2 + 1, 0, IC<B1OFF>{});
    SBAR(); LGKM_SB(0);
    PRIO1(); mmaQ(IC<4>{}, IC<2>{}, b1F); PRIO0();
    SBAR();
    if constexpr (STG.v) {
      stB(k2 + 1, 1, IC<B1OFF>{});
      stA(k2 + 1, 0, IC<A1OFF>{});
      stA(k2 + 1, 1, IC<A1OFF>{});
      asm volatile("s_waitcnt vmcnt(8)" ::: "memory");
    }
    SBAR();
    PRIO1(); mmaQ(IC<4>{}, IC<0>{}, b0F); PRIO0();
    SBAR();
  };

  stA(0, 0, IC<A0OFF>{}); stA(0, 1, IC<A0OFF>{});
  stB(0, 0, IC<B0OFF>{}); stB(0, 1, IC<B0OFF>{});
  stA(1, 0, IC<A1OFF>{}); stA(1, 1, IC<A1OFF>{});
  stB(1, 0, IC<B1OFF>{}); stB(1, 1, IC<B1OFF>{});
  asm volatile("s_waitcnt vmcnt(8)" ::: "memory");
  SBAR();

  for (int it = 0; it < G2_NT / 2 - 1; ++it)
    pairBody(2 * it + 2, BC<true>{});
  pairBody(0, BC<false>{});

#pragma unroll
  for (int mf = 0; mf < 8; mf++)
#pragma unroll
    for (int j = 0; j < 4; j++) {
      int col = n0 + wc * 64 + (j >> 1) * 32 + (j & 1) * 16 + l15;
#pragma unroll
      for (int r = 0; r < 4; r++) {
        int row = m0 + wr * 128 + mf * 16 + quad * 4 + r;
        OUT[(size_t)row * DIM + col] = acc[mf][j][r];
      }
    }
}

// ---------------------------------------------------------------------------
// Chunk-prefix + rescan (scan_phase1 fused into gemm1's epilogue)
// ---------------------------------------------------------------------------

// In-place: Asum[c][ch] -> P[c][ch] (prefix BEFORE chunk c)
__global__ __launch_bounds__(256) void scan_phase2(
    float* Asum, const float* __restrict__ Lend, int nbch) {
  int ch = blockIdx.x * 256 + threadIdx.x;
  float p = -INFINITY;
  for (int c = 0; c < NCHUNK; c++) {
    float a = Asum[(size_t)c * nbch + ch];
    float le = Lend[(size_t)c * nbch + ch];
    Asum[(size_t)c * nbch + ch] = p;
    p = logaddexp_f(a + p, le);
  }
}

// Rescan with real prefix; write h = exp(log_h) as bf16 into H (8B/lane).
__global__ __launch_bounds__(256) void scan_phase3(
    const unsigned int* __restrict__ LCLV, const float* __restrict__ P,
    ushort_t* __restrict__ H, int nbch) {
  const int EQ = DIM_INNER / 4;
  int tid = blockIdx.x * 256 + threadIdx.x;
  int ep = tid % EQ;
  int tmp = tid / EQ;
  int c = tmp % NCHUNK;
  int bz = tmp / NCHUNK;
  size_t base4 = ((size_t)bz * SEQ + (size_t)c * CHUNK) * EQ + ep;
  const uint4_t* L4 = (const uint4_t*)LCLV;
  u16x4* H4 = (u16x4*)H;

  size_t pidx = ((size_t)c * nbch + (size_t)bz * DIM_INNER) / 4 + ep;
  float4_t logh = ((const float4_t*)P)[pidx];
#pragma unroll 4
  for (int t = 0; t < CHUNK; t++) {
    uint4_t u = L4[base4 + (size_t)t * EQ];
    u16x4 hv;
#pragma unroll
    for (int k = 0; k < 4; k++) {
      float lc = bflo2f(u[k]), lv = bfhi2f(u[k]);
      logh[k] = logaddexp_f(lc + logh[k], lv);
      hv[k] = f2bf(__expf(logh[k]));
    }
    H4[base4 + (size_t)t * EQ] = hv;
  }
}

extern "C" void kernel_launch(void* const* d_in, const int* in_sizes, int n_in,
                              void* d_out, int out_size, void* d_ws, size_t ws_size,
                              hipStream_t stream) {
  const float* X = (const float*)d_in[0];     // [4,4096,1024]
  const float* Whg = (const float*)d_in[1];   // [1024,4096]
  const float* Wout = (const float*)d_in[2];  // [2048,1024]
  float* out = (float*)d_out;                 // [4,4096,1024] fp32

  ushort_t* Xbf = (ushort_t*)d_ws;
  ushort_t* Whg_t = Xbf + (size_t)MTOT * DIM;                   // [4096][1024]
  ushort_t* Wout_t = Whg_t + (size_t)(2 * DIM_INNER) * DIM;     // [1024][2048]
  char* pp = (char*)(Wout_t + (size_t)DIM * DIM_INNER);

  const size_t fixed_bytes = (size_t)MTOT * DIM * 2 +
                             (size_t)2 * DIM_INNER * DIM * 2 +
                             (size_t)DIM * DIM_INNER * 2;
  // per batch: LCLV 4B + H 2B per elem + 2 summaries
  const size_t per_batch = (size_t)SEQ * DIM_INNER * 4 +
                           (size_t)SEQ * DIM_INNER * 2 +
                           2 * (size_t)DIM_INNER * NCHUNK * 4;
  int nb = 4;
  while (nb > 1 && fixed_bytes + (size_t)nb * per_batch > ws_size) nb >>= 1;
  const int npass = BATCH / nb;

  convert_f32_bf16<<<(MTOT * DIM / 4) / 256, 256, 0, stream>>>(X, Xbf);
  transpose_f32_bf16<<<dim3(2 * DIM_INNER / 32, DIM / 32), 256, 0, stream>>>(
      Whg, Whg_t, DIM, 2 * DIM_INNER);
  transpose_f32_bf16<<<dim3(DIM / 32, DIM_INNER / 32), 256, 0, stream>>>(
      Wout, Wout_t, DIM_INNER, DIM);

  for (int pass = 0; pass < npass; pass++) {
    const int b0 = pass * nb;
    const int nrows = nb * SEQ;
    const int nbch = nb * DIM_INNER;

    unsigned int* LCLV = (unsigned int*)pp;
    ushort_t* Hbf = (ushort_t*)(LCLV + (size_t)nb * SEQ * DIM_INNER);
    float* Asum = (float*)(Hbf + (size_t)nb * SEQ * DIM_INNER);
    float* Lend = Asum + (size_t)nb * DIM_INNER * NCHUNK;

    gemm1_fused<<<dim3(DIM_INNER / 128, nrows / 256), 512, 0, stream>>>(
        Xbf + (size_t)b0 * SEQ * DIM, Whg_t, LCLV, Asum, Lend, nbch);
    scan_phase2<<<nbch / 256, 256, 0, stream>>>(Asum, Lend, nbch);
    scan_phase3<<<(nbch / 4 * NCHUNK) / 256, 256, 0, stream>>>(LCLV, Asum, Hbf, nbch);
    gemm2<<<dim3(DIM / 256, nrows / 256), 512, 0, stream>>>(
        Hbf, Wout_t, out + (size_t)b0 * SEQ * DIM);
  }
}

// Round 6
// 447.194 us; speedup vs baseline: 1.0104x; 1.0096x over previous
//
#include <hip/hip_runtime.h>
#include <cmath>

#define DIM 1024
#define DIM_INNER 2048
#define BATCH 4
#define SEQ 4096
#define MTOT (BATCH * SEQ)
#define CHUNK 32
#define NCHUNK (SEQ / CHUNK)        // 128 chunks per sequence

typedef __bf16 bf16x8 __attribute__((ext_vector_type(8)));
typedef short short8_t __attribute__((ext_vector_type(8)));
typedef float floatx4 __attribute__((ext_vector_type(4)));
typedef unsigned short u16x4 __attribute__((ext_vector_type(4)));
typedef unsigned int uint4_t __attribute__((ext_vector_type(4)));
typedef float float4_t __attribute__((ext_vector_type(4)));
typedef unsigned short ushort_t;

template <int N> struct IC { static constexpr int v = N; };
template <bool B> struct BC { static constexpr bool v = B; };

#define LGKM_SB(n) do { asm volatile("s_waitcnt lgkmcnt(" #n ")" ::: "memory"); \
                        __builtin_amdgcn_sched_barrier(0); } while (0)
#define SCHED0() __builtin_amdgcn_sched_barrier(0)
#define SBAR() __builtin_amdgcn_s_barrier()
#define PRIO1() __builtin_amdgcn_s_setprio(1)
#define PRIO0() __builtin_amdgcn_s_setprio(0)

__device__ __forceinline__ unsigned short f2bf(float f) {
  unsigned int u = __builtin_bit_cast(unsigned int, f);
  u += 0x7fffu + ((u >> 16) & 1u);   // round-to-nearest-even
  return (unsigned short)(u >> 16);
}
__device__ __forceinline__ float bflo2f(unsigned int u) {
  return __builtin_bit_cast(float, u << 16);
}
__device__ __forceinline__ float bfhi2f(unsigned int u) {
  return __builtin_bit_cast(float, u & 0xffff0000u);
}

// Fast (native v_exp/v_log) log-space terms from (h, g):
//   lc = -softplus(g) ;  lv = -softplus(-g) + log_g(h) = g + lc + log_g(h)
__device__ __forceinline__ void lclv_fast(float h, float g, float& lc, float& lv) {
  float eg = __expf(-fabsf(g));
  float sp = fmaxf(g, 0.f) + __logf(1.f + eg);
  lc = -sp;
  float eh = __expf(h);
  float t  = (h >= 0.f) ? (h + 0.5f) : (1.f + eh);
  float lt = __logf(t);
  float lg = (h >= 0.f) ? lt : (h - lt);
  lv = g + lc + lg;
}
// a may be -inf; b finite
__device__ __forceinline__ float logaddexp_f(float a, float b) {
  float m = fmaxf(a, b);
  return m + __logf(1.f + __expf(-fabsf(a - b)));
}

// async 16B/lane global->LDS; dest = wave-uniform base + lane*16
__device__ __forceinline__ void async_copy16(const ushort_t* g, ushort_t* l) {
  __builtin_amdgcn_global_load_lds(
      (const __attribute__((address_space(1))) void*)g,
      (__attribute__((address_space(3))) void*)l, 16, 0, 0);
}

// ---------------------------------------------------------------------------
// One-time input conversions
// ---------------------------------------------------------------------------
__global__ __launch_bounds__(256) void convert_f32_bf16(
    const float* __restrict__ src, ushort_t* __restrict__ dst) {
  int i = blockIdx.x * 256 + threadIdx.x;   // one float4 per thread
  float4 v = ((const float4*)src)[i];
  u16x4 o = {f2bf(v.x), f2bf(v.y), f2bf(v.z), f2bf(v.w)};
  ((u16x4*)dst)[i] = o;
}

// dst[n][k] = bf16(src[k][n]); src is [K][N] fp32
__global__ __launch_bounds__(256) void transpose_f32_bf16(
    const float* __restrict__ src, ushort_t* __restrict__ dst, int K, int N) {
  __shared__ float tile[32][33];
  int tx = threadIdx.x & 31, ty = threadIdx.x >> 5;   // 32 x 8
  int n0 = blockIdx.x * 32, k0 = blockIdx.y * 32;
#pragma unroll
  for (int i = 0; i < 4; i++) {
    int k = ty + i * 8;
    tile[k][tx] = src[(size_t)(k0 + k) * N + n0 + tx];
  }
  __syncthreads();
#pragma unroll
  for (int i = 0; i < 4; i++) {
    int r = ty + i * 8;
    dst[(size_t)(n0 + r) * K + k0 + tx] = f2bf(tile[tx][r]);
  }
}

// ---------------------------------------------------------------------------
// GEMM1 fused — r2's measured-best inner structure (4 phases/K-tile, 3-buf A
// rotation, 2-buf B, counted lgkmcnt micro-groups, counted vmcnt(4)); natural
// block mapping (no XCD swizzle); fused chunk-summary epilogue (r4, verified).
// ---------------------------------------------------------------------------
#define G1_NT (DIM / 64)        // 16 K-tiles
#define G2_NT (DIM_INNER / 64)  // 32 K-tiles

__global__ __launch_bounds__(512, 2) void gemm1_fused(
    const ushort_t* __restrict__ Xbf, const ushort_t* __restrict__ Wt,
    unsigned int* __restrict__ LCLV,
    float* __restrict__ Asum, float* __restrict__ Lend, int nbch) {
  __shared__ __align__(16) ushort_t lds[81920];   // 160 KB exactly

  const int tid = threadIdx.x;
  const int wv = tid >> 6;
  const int lane = tid & 63;
  const int wr = wv >> 2;           // 0..1 (M half)
  const int wc = wv & 3;            // 0..3 (N quarter)
  const int l15 = lane & 15;
  const int quad = lane >> 4;
  const int n0 = blockIdx.x * 128;  // h-column base (g rows = +DIM_INNER in Wt)
  const int m0 = blockIdx.y * 256;

  // ---- precomputed staging offsets (32-bit; kt*64 added per call, affine)
  int aSrc[2][2], bSrc[2][2];   // [half][L]
  int dstE[2];
#pragma unroll
  for (int L = 0; L < 2; L++) {
    int e = L * 512 + tid;
    int row = e >> 3, slot = e & 7;
    int sw = (slot ^ (row & 7)) << 3;
    dstE[L] = e * 8;
#pragma unroll
    for (int half = 0; half < 2; half++) {
      aSrc[half][L] = (m0 + half * 128 + row) * DIM + sw;
      int br = half * 128 + row;
      int grow = n0 + ((br >> 6) << 5) + (br & 31) + ((br & 32) ? DIM_INNER : 0);
      bSrc[half][L] = grow * DIM + sw;
    }
  }

  auto stageA = [&](int kt, int half, int buf) {
#pragma unroll
    for (int L = 0; L < 2; L++)
      async_copy16(Xbf + aSrc[half][L] + kt * 64,
                   lds + buf * 16384 + half * 8192 + dstE[L]);
  };
  auto stageB = [&](int kt, int half, int buf) {
#pragma unroll
    for (int L = 0; L < 2; L++)
      async_copy16(Wt + bSrc[half][L] + kt * 64,
                   lds + 49152 + buf * 16384 + half * 8192 + dstE[L]);
  };

  // ---- precomputed ds_read bases (swz depends only on ks,quad,l15&7)
  const int swz0 = ((quad ^ (l15 & 7)) << 3);
  const int swz1 = (((4 | quad) ^ (l15 & 7)) << 3);
  const int aB0 = wr * 8192 + l15 * 64 + swz0;
  const int aB1 = wr * 8192 + l15 * 64 + swz1;
  const int bB0 = wc * 4096 + l15 * 64 + swz0;
  const int bB1 = wc * 4096 + l15 * 64 + swz1;

  auto readA = [&](int buf, int mf, int ks) -> bf16x8 {
    const ushort_t* p = lds + buf * 16384 + (ks ? aB1 : aB0) + mf * 1024;
    return __builtin_bit_cast(bf16x8, *(const short8_t*)p);
  };
  auto readB = [&](int buf, int nf, int ks) -> bf16x8 {
    const ushort_t* p = lds + 49152 + buf * 16384 + (ks ? bB1 : bB0) + nf * 1024;
    return __builtin_bit_cast(bf16x8, *(const short8_t*)p);
  };

  floatx4 acc[8][4];
#pragma unroll
  for (int i = 0; i < 8; i++)
#pragma unroll
    for (int j = 0; j < 4; j++) acc[i][j] = (floatx4){0.f, 0.f, 0.f, 0.f};

  bf16x8 aF[4][2], b0F[2][2], b1F[2][2];

  // 4 MFMA: aF[MA] x bX[0..1] -> acc[MC][J], acc[MC][J+1]
  auto mma4 = [&](auto MA, auto MC, auto J, bf16x8 (&bX)[2][2]) {
#pragma unroll
    for (int jj = 0; jj < 2; jj++)
#pragma unroll
      for (int ks = 0; ks < 2; ks++)
        acc[MC.v][J.v + jj] = __builtin_amdgcn_mfma_f32_16x16x32_bf16(
            aF[MA.v][ks], bX[jj][ks], acc[MC.v][J.v + jj], 0, 0, 0);
  };
  // 8 MFMA: aF[0..3] x bvec -> acc[0..3][J]
  auto mmaRow = [&](auto J, bf16x8 (&bvec)[2]) {
#pragma unroll
    for (int m = 0; m < 4; m++)
#pragma unroll
      for (int ks = 0; ks < 2; ks++)
        acc[m][J.v] = __builtin_amdgcn_mfma_f32_16x16x32_bf16(
            aF[m][ks], bvec[ks], acc[m][J.v], 0, 0, 0);
  };

  int bufA = 0, bufB = 0, bufAn = 2, bufBn = 1;

  auto tileBody = [&](int kb, int ka, auto STB, auto STA, auto VMALL) {
    // ---------- phase 0 : Q(mh0 x nh0); stage B(kb) half0
    aF[0][0] = readA(bufA, 0, 0); aF[0][1] = readA(bufA, 0, 1);
    b0F[0][0] = readB(bufB, 0, 0); b0F[0][1] = readB(bufB, 0, 1);
    b0F[1][0] = readB(bufB, 1, 0); b0F[1][1] = readB(bufB, 1, 1);
    SCHED0();
    aF[1][0] = readA(bufA, 1, 0); aF[1][1] = readA(bufA, 1, 1);
    SCHED0();
    aF[2][0] = readA(bufA, 2, 0); aF[2][1] = readA(bufA, 2, 1);
    SCHED0();
    aF[3][0] = readA(bufA, 3, 0); aF[3][1] = readA(bufA, 3, 1);
    SCHED0();
    if constexpr (STB.v) stageB(kb, 0, bufBn);
    SBAR();
    PRIO1();
    LGKM_SB(6); mma4(IC<0>{}, IC<0>{}, IC<0>{}, b0F);
    LGKM_SB(4); mma4(IC<1>{}, IC<1>{}, IC<0>{}, b0F);
    LGKM_SB(2); mma4(IC<2>{}, IC<2>{}, IC<0>{}, b0F);
    LGKM_SB(0); mma4(IC<3>{}, IC<3>{}, IC<0>{}, b0F);
    PRIO0();
    SBAR();

    // ---------- phase 1 : Q(mh0 x nh1); stage B(kb) half1
    b1F[0][0] = readB(bufB, 2, 0); b1F[0][1] = readB(bufB, 2, 1);
    SCHED0();
    b1F[1][0] = readB(bufB, 3, 0); b1F[1][1] = readB(bufB, 3, 1);
    SCHED0();
    if constexpr (STB.v) stageB(kb, 1, bufBn);
    SBAR();
    PRIO1();
    LGKM_SB(2); mmaRow(IC<2>{}, b1F[0]);
    LGKM_SB(0); mmaRow(IC<3>{}, b1F[1]);
    PRIO0();
    SBAR();

    // ---------- phase 2 : Q(mh1 x nh1); stage A(ka) half0
    aF[0][0] = readA(bufA, 4, 0); aF[0][1] = readA(bufA, 4, 1);
    SCHED0();
    aF[1][0] = readA(bufA, 5, 0); aF[1][1] = readA(bufA, 5, 1);
    SCHED0();
    aF[2][0] = readA(bufA, 6, 0); aF[2][1] = readA(bufA, 6, 1);
    SCHED0();
    aF[3][0] = readA(bufA, 7, 0); aF[3][1] = readA(bufA, 7, 1);
    SCHED0();
    if constexpr (STA.v) stageA(ka, 0, bufAn);
    SBAR();
    PRIO1();
    LGKM_SB(6); mma4(IC<0>{}, IC<4>{}, IC<2>{}, b1F);
    LGKM_SB(4); mma4(IC<1>{}, IC<5>{}, IC<2>{}, b1F);
    LGKM_SB(2); mma4(IC<2>{}, IC<6>{}, IC<2>{}, b1F);
    LGKM_SB(0); mma4(IC<3>{}, IC<7>{}, IC<2>{}, b1F);
    PRIO0();
    SBAR();

    // ---------- phase 3 : Q(mh1 x nh0); stage A(ka) half1; counted vmcnt
    if constexpr (STA.v) stageA(ka, 1, bufAn);
    SCHED0();
    if constexpr (STA.v) {
      asm volatile("s_waitcnt vmcnt(4)" ::: "memory");
    } else if constexpr (VMALL.v) {
      asm volatile("s_waitcnt vmcnt(0)" ::: "memory");
    }
    SBAR();
    PRIO1();
    mma4(IC<0>{}, IC<4>{}, IC<0>{}, b0F);
    mma4(IC<1>{}, IC<5>{}, IC<0>{}, b0F);
    mma4(IC<2>{}, IC<6>{}, IC<0>{}, b0F);
    mma4(IC<3>{}, IC<7>{}, IC<0>{}, b0F);
    PRIO0();
    SBAR();
  };

  // prologue: B(0), A(0), A(1); keep A(1)'s 4 loads in flight
  stageB(0, 0, 0); stageB(0, 1, 0);
  stageA(0, 0, 0); stageA(0, 1, 0);
  stageA(1, 0, 1); stageA(1, 1, 1);
  asm volatile("s_waitcnt vmcnt(4)" ::: "memory");
  SBAR();

  for (int u = 0; u < G1_NT - 2; u++) {
    tileBody(u + 1, u + 2, BC<true>{}, BC<true>{}, BC<false>{});
    bufA = (bufA == 2) ? 0 : bufA + 1;
    bufAn = (bufAn == 2) ? 0 : bufAn + 1;
    bufB ^= 1; bufBn ^= 1;
  }
  tileBody(G1_NT - 1, 0, BC<true>{}, BC<false>{}, BC<true>{});
  bufA = (bufA == 2) ? 0 : bufA + 1;
  bufB ^= 1;
  tileBody(0, 0, BC<false>{}, BC<false>{}, BC<false>{});

  // ---- epilogue: lc/lv pack + fused chunk summaries (verified in r4).
  // Chunk = 32 rows = mf pair {2c2, 2c2+1}; row order mh*16 + quad*4 + r.
  // Per 16-row half: in-lane compose over r, ordered quad butterfly; then
  // half0 o half1.
#pragma unroll
  for (int c2 = 0; c2 < 4; c2++) {
    float hA[2][2], hL[2][2];   // [mh][j]
#pragma unroll
    for (int mh = 0; mh < 2; mh++) {
      int mf = c2 * 2 + mh;
#pragma unroll
      for (int j = 0; j < 2; j++) {
        int col = n0 + wc * 32 + j * 16 + l15;
        float sA = 0.f, sL = -INFINITY;
#pragma unroll
        for (int r = 0; r < 4; r++) {
          int row = m0 + wr * 128 + mf * 16 + quad * 4 + r;
          float lc, lv;
          lclv_fast(acc[mf][j][r], acc[mf][j + 2][r], lc, lv);
          unsigned int pk = ((unsigned int)f2bf(lv) << 16) | (unsigned int)f2bf(lc);
          LCLV[(size_t)row * DIM_INNER + col] = pk;
          sL = logaddexp_f(sL + lc, lv);
          sA += lc;
        }
        // ordered butterfly across quad lanes (bits 4,5): lower-quad first
        float A = sA, L = sL;
#pragma unroll
        for (int st = 16; st <= 32; st <<= 1) {
          float Ao = __shfl_xor(A, st, 64);
          float Lo = __shfl_xor(L, st, 64);
          bool upper = (lane & st) != 0;
          L = upper ? logaddexp_f(Lo + A, L) : logaddexp_f(L + Ao, Lo);
          A = A + Ao;
        }
        hA[mh][j] = A;
        hL[mh][j] = L;
      }
    }
#pragma unroll
    for (int j = 0; j < 2; j++) {
      float A = hA[0][j] + hA[1][j];
      float L = logaddexp_f(hL[0][j] + hA[1][j], hL[1][j]);
      if (quad == 0) {
        int cg = (m0 + wr * 128 + c2 * 32) >> 5;   // global chunk-row index
        int bz = cg >> 7;                          // NCHUNK = 128 chunks/seq
        int cs = cg & (NCHUNK - 1);
        int col = n0 + wc * 32 + j * 16 + l15;
        size_t sidx = (size_t)cs * nbch + (size_t)bz * DIM_INNER + col;
        Asum[sidx] = A;
        Lend[sidx] = L;
      }
    }
  }
}

// ---------------------------------------------------------------------------
// GEMM2 — r5's measured-best structure (static dbuf, 8-phase pairBody,
// counted vmcnt(4)/vmcnt(8)): out = H @ W_out, K = 2048 (32 tiles).
// grid = (DIM/256) x (rows/256) = 256 blocks -> 1 per CU.
// ---------------------------------------------------------------------------
#define A0OFF 0
#define A1OFF 16384
#define B0OFF 32768
#define B1OFF 49152

__global__ __launch_bounds__(512, 2) void gemm2(
    const ushort_t* __restrict__ Hbf, const ushort_t* __restrict__ Wot,
    float* __restrict__ OUT) {
  __shared__ __align__(16) ushort_t lds[65536];

  const int tid = threadIdx.x;
  const int lane = tid & 63;
  const int wv = tid >> 6;
  const int wr = wv >> 2;
  const int wc = wv & 3;
  const int l15 = lane & 15;
  const int quad = lane >> 4;
  const int n0 = blockIdx.x * 256;
  const int m0 = blockIdx.y * 256;

  int aSrc[2][2], bSrc[2][2];
  int dstE[2];
#pragma unroll
  for (int L = 0; L < 2; L++) {
    int e = L * 512 + tid;
    int row = e >> 3, slot = e & 7;
    int sw = (slot ^ (row & 7)) << 3;
    dstE[L] = e * 8;
#pragma unroll
    for (int half = 0; half < 2; half++) {
      aSrc[half][L] = (m0 + half * 128 + row) * DIM_INNER + sw;
      bSrc[half][L] = (n0 + half * 128 + row) * DIM_INNER + sw;
    }
  }

  auto stA = [&](int kt, int half, auto AO) {
#pragma unroll
    for (int L = 0; L < 2; L++)
      async_copy16(Hbf + aSrc[half][L] + kt * 64,
                   lds + AO.v + half * 8192 + dstE[L]);
  };
  auto stB = [&](int kt, int half, auto BO) {
#pragma unroll
    for (int L = 0; L < 2; L++)
      async_copy16(Wot + bSrc[half][L] + kt * 64,
                   lds + BO.v + half * 8192 + dstE[L]);
  };

  const int swz0 = ((quad ^ (l15 & 7)) << 3);
  const int swz1 = (((4 | quad) ^ (l15 & 7)) << 3);
  const int aB0 = wr * 8192 + l15 * 64 + swz0;
  const int aB1 = wr * 8192 + l15 * 64 + swz1;
  const int bB0 = wc * 4096 + l15 * 64 + swz0;
  const int bB1 = wc * 4096 + l15 * 64 + swz1;

  floatx4 acc[8][4];
#pragma unroll
  for (int i = 0; i < 8; i++)
#pragma unroll
    for (int j = 0; j < 4; j++) acc[i][j] = (floatx4){0.f, 0.f, 0.f, 0.f};

  bf16x8 aF[4][2], b0F[2][2], b1F[2][2];

  auto rdA4 = [&](auto AO, int mb) {
#pragma unroll
    for (int m = 0; m < 4; m++) {
      aF[m][0] = __builtin_bit_cast(bf16x8,
          *(const short8_t*)(lds + AO.v + aB0 + (mb + m) * 1024));
      aF[m][1] = __builtin_bit_cast(bf16x8,
          *(const short8_t*)(lds + AO.v + aB1 + (mb + m) * 1024));
    }
  };
  auto rdB2 = [&](auto BO, int nb, bf16x8 (&bX)[2][2]) {
#pragma unroll
    for (int n = 0; n < 2; n++) {
      bX[n][0] = __builtin_bit_cast(bf16x8,
          *(const short8_t*)(lds + BO.v + bB0 + (nb + n) * 1024));
      bX[n][1] = __builtin_bit_cast(bf16x8,
          *(const short8_t*)(lds + BO.v + bB1 + (nb + n) * 1024));
    }
  };
  auto mmaQ = [&](auto MB, auto JB, bf16x8 (&bX)[2][2]) {
#pragma unroll
    for (int m = 0; m < 4; m++)
#pragma unroll
      for (int jj = 0; jj < 2; jj++)
#pragma unroll
        for (int ks = 0; ks < 2; ks++)
          acc[MB.v + m][JB.v + jj] = __builtin_amdgcn_mfma_f32_16x16x32_bf16(
              aF[m][ks], bX[jj][ks], acc[MB.v + m][JB.v + jj], 0, 0, 0);
  };

  auto pairBody = [&](int k2, auto STG) {
    rdA4(IC<A0OFF>{}, 0); rdB2(IC<B0OFF>{}, 0, b0F);
    SCHED0();
    SBAR(); LGKM_SB(0);
    PRIO1(); mmaQ(IC<0>{}, IC<0>{}, b0F); PRIO0();
    SBAR();
    rdB2(IC<B0OFF>{}, 2, b1F);
    SCHED0();
    SBAR(); LGKM_SB(0);
    PRIO1(); mmaQ(IC<0>{}, IC<2>{}, b1F); PRIO0();
    SBAR();
    rdA4(IC<A0OFF>{}, 4);
    SCHED0();
    if constexpr (STG.v) stB(k2, 0, IC<B0OFF>{});
    SBAR(); LGKM_SB(0);
    PRIO1(); mmaQ(IC<4>{}, IC<2>{}, b1F); PRIO0();
    SBAR();
    if constexpr (STG.v) {
      stB(k2, 1, IC<B0OFF>{});
      asm volatile("s_waitcnt vmcnt(4)" ::: "memory");
    } else {
      asm volatile("s_waitcnt vmcnt(0)" ::: "memory");
    }
    SBAR();
    PRIO1(); mmaQ(IC<4>{}, IC<0>{}, b0F); PRIO0();
    SBAR();
    rdA4(IC<A1OFF>{}, 0); rdB2(IC<B1OFF>{}, 0, b0F);
    SCHED0();
    if constexpr (STG.v) stA(k2, 0, IC<A0OFF>{});
    SBAR(); LGKM_SB(0);
    PRIO1(); mmaQ(IC<0>{}, IC<0>{}, b0F); PRIO0();
    SBAR();
    rdB2(IC<B1OFF>{}, 2, b1F);
    SCHED0();
    if constexpr (STG.v) stA(k2, 1, IC<A0OFF>{});
    SBAR(); LGKM_SB(0);
    PRIO1(); mmaQ(IC<0>{}, IC<2>{}, b1F); PRIO0();
    SBAR();
    rdA4(IC<A1OFF>{}, 4);
    SCHED0();
    if constexpr (STG.v) stB(k2 + 1, 0, IC<B1OFF>{});
    SBAR(); LGKM_SB(0);
    PRIO1(); mmaQ(IC<4>{}, IC<2>{}, b1F); PRIO0();
    SBAR();
    if constexpr (STG.v) {
      stB(k2 + 1, 1, IC<B1OFF>{});
      stA(k2 + 1, 0, IC<A1OFF>{});
      stA(k2 + 1, 1, IC<A1OFF>{});
      asm volatile("s_waitcnt vmcnt(8)" ::: "memory");
    }
    SBAR();
    PRIO1(); mmaQ(IC<4>{}, IC<0>{}, b0F); PRIO0();
    SBAR();
  };

  stA(0, 0, IC<A0OFF>{}); stA(0, 1, IC<A0OFF>{});
  stB(0, 0, IC<B0OFF>{}); stB(0, 1, IC<B0OFF>{});
  stA(1, 0, IC<A1OFF>{}); stA(1, 1, IC<A1OFF>{});
  stB(1, 0, IC<B1OFF>{}); stB(1, 1, IC<B1OFF>{});
  asm volatile("s_waitcnt vmcnt(8)" ::: "memory");
  SBAR();

  for (int it = 0; it < G2_NT / 2 - 1; ++it)
    pairBody(2 * it + 2, BC<true>{});
  pairBody(0, BC<false>{});

#pragma unroll
  for (int mf = 0; mf < 8; mf++)
#pragma unroll
    for (int j = 0; j < 4; j++) {
      int col = n0 + wc * 64 + (j >> 1) * 32 + (j & 1) * 16 + l15;
#pragma unroll
      for (int r = 0; r < 4; r++) {
        int row = m0 + wr * 128 + mf * 16 + quad * 4 + r;
        OUT[(size_t)row * DIM + col] = acc[mf][j][r];
      }
    }
}

// ---------------------------------------------------------------------------
// Chunk-prefix + rescan (scan_phase1 fused into gemm1's epilogue)
// ---------------------------------------------------------------------------

// In-place: Asum[c][ch] -> P[c][ch] (prefix BEFORE chunk c)
__global__ __launch_bounds__(256) void scan_phase2(
    float* Asum, const float* __restrict__ Lend, int nbch) {
  int ch = blockIdx.x * 256 + threadIdx.x;
  float p = -INFINITY;
  for (int c = 0; c < NCHUNK; c++) {
    float a = Asum[(size_t)c * nbch + ch];
    float le = Lend[(size_t)c * nbch + ch];
    Asum[(size_t)c * nbch + ch] = p;
    p = logaddexp_f(a + p, le);
  }
}

// Rescan with real prefix; write h = exp(log_h) as bf16 into H (8B/lane).
__global__ __launch_bounds__(256) void scan_phase3(
    const unsigned int* __restrict__ LCLV, const float* __restrict__ P,
    ushort_t* __restrict__ H, int nbch) {
  const int EQ = DIM_INNER / 4;
  int tid = blockIdx.x * 256 + threadIdx.x;
  int ep = tid % EQ;
  int tmp = tid / EQ;
  int c = tmp % NCHUNK;
  int bz = tmp / NCHUNK;
  size_t base4 = ((size_t)bz * SEQ + (size_t)c * CHUNK) * EQ + ep;
  const uint4_t* L4 = (const uint4_t*)LCLV;
  u16x4* H4 = (u16x4*)H;

  size_t pidx = ((size_t)c * nbch + (size_t)bz * DIM_INNER) / 4 + ep;
  float4_t logh = ((const float4_t*)P)[pidx];
#pragma unroll 4
  for (int t = 0; t < CHUNK; t++) {
    uint4_t u = L4[base4 + (size_t)t * EQ];
    u16x4 hv;
#pragma unroll
    for (int k = 0; k < 4; k++) {
      float lc = bflo2f(u[k]), lv = bfhi2f(u[k]);
      logh[k] = logaddexp_f(lc + logh[k], lv);
      hv[k] = f2bf(__expf(logh[k]));
    }
    H4[base4 + (size_t)t * EQ] = hv;
  }
}

extern "C" void kernel_launch(void* const* d_in, const int* in_sizes, int n_in,
                              void* d_out, int out_size, void* d_ws, size_t ws_size,
                              hipStream_t stream) {
  const float* X = (const float*)d_in[0];     // [4,4096,1024]
  const float* Whg = (const float*)d_in[1];   // [1024,4096]
  const float* Wout = (const float*)d_in[2];  // [2048,1024]
  float* out = (float*)d_out;                 // [4,4096,1024] fp32

  ushort_t* Xbf = (ushort_t*)d_ws;
  ushort_t* Whg_t = Xbf + (size_t)MTOT * DIM;                   // [4096][1024]
  ushort_t* Wout_t = Whg_t + (size_t)(2 * DIM_INNER) * DIM;     // [1024][2048]
  char* pp = (char*)(Wout_t + (size_t)DIM * DIM_INNER);

  const size_t fixed_bytes = (size_t)MTOT * DIM * 2 +
                             (size_t)2 * DIM_INNER * DIM * 2 +
                             (size_t)DIM * DIM_INNER * 2;
  // per batch: LCLV 4B + H 2B per elem + 2 summaries
  const size_t per_batch = (size_t)SEQ * DIM_INNER * 4 +
                           (size_t)SEQ * DIM_INNER * 2 +
                           2 * (size_t)DIM_INNER * NCHUNK * 4;
  int nb = 4;
  while (nb > 1 && fixed_bytes + (size_t)nb * per_batch > ws_size) nb >>= 1;
  const int npass = BATCH / nb;

  convert_f32_bf16<<<(MTOT * DIM / 4) / 256, 256, 0, stream>>>(X, Xbf);
  transpose_f32_bf16<<<dim3(2 * DIM_INNER / 32, DIM / 32), 256, 0, stream>>>(
      Whg, Whg_t, DIM, 2 * DIM_INNER);
  transpose_f32_bf16<<<dim3(DIM / 32, DIM_INNER / 32), 256, 0, stream>>>(
      Wout, Wout_t, DIM_INNER, DIM);

  for (int pass = 0; pass < npass; pass++) {
    const int b0 = pass * nb;
    const int nrows = nb * SEQ;
    const int nbch = nb * DIM_INNER;

    unsigned int* LCLV = (unsigned int*)pp;
    ushort_t* Hbf = (ushort_t*)(LCLV + (size_t)nb * SEQ * DIM_INNER);
    float* Asum = (float*)(Hbf + (size_t)nb * SEQ * DIM_INNER);
    float* Lend = Asum + (size_t)nb * DIM_INNER * NCHUNK;

    gemm1_fused<<<dim3(DIM_INNER / 128, nrows / 256), 512, 0, stream>>>(
        Xbf + (size_t)b0 * SEQ * DIM, Whg_t, LCLV, Asum, Lend, nbch);
    scan_phase2<<<nbch / 256, 256, 0, stream>>>(Asum, Lend, nbch);
    scan_phase3<<<(nbch / 4 * NCHUNK) / 256, 256, 0, stream>>>(LCLV, Asum, Hbf, nbch);
    gemm2<<<dim3(DIM / 256, nrows / 256), 512, 0, stream>>>(
        Hbf, Wout_t, out + (size_t)b0 * SEQ * DIM);
  }
}

// Round 7
// 421.404 us; speedup vs baseline: 1.0722x; 1.0612x over previous
//
#include <hip/hip_runtime.h>
#include <cmath>

#define DIM 1024
#define DIM_INNER 2048
#define BATCH 4
#define SEQ 4096
#define MTOT (BATCH * SEQ)
#define CHUNK 32
#define NCHUNK (SEQ / CHUNK)        // 128 chunks per sequence

typedef __bf16 bf16x8 __attribute__((ext_vector_type(8)));
typedef short short8_t __attribute__((ext_vector_type(8)));
typedef float floatx4 __attribute__((ext_vector_type(4)));
typedef unsigned short u16x4 __attribute__((ext_vector_type(4)));
typedef unsigned int uint4_t __attribute__((ext_vector_type(4)));
typedef float float4_t __attribute__((ext_vector_type(4)));
typedef unsigned short ushort_t;

template <int N> struct IC { static constexpr int v = N; };
template <bool B> struct BC { static constexpr bool v = B; };

#define LGKM_SB(n) do { asm volatile("s_waitcnt lgkmcnt(" #n ")" ::: "memory"); \
                        __builtin_amdgcn_sched_barrier(0); } while (0)
#define SCHED0() __builtin_amdgcn_sched_barrier(0)
#define SBAR() __builtin_amdgcn_s_barrier()
#define PRIO1() __builtin_amdgcn_s_setprio(1)
#define PRIO0() __builtin_amdgcn_s_setprio(0)

__device__ __forceinline__ unsigned short f2bf(float f) {
  unsigned int u = __builtin_bit_cast(unsigned int, f);
  u += 0x7fffu + ((u >> 16) & 1u);   // round-to-nearest-even
  return (unsigned short)(u >> 16);
}
__device__ __forceinline__ float bflo2f(unsigned int u) {
  return __builtin_bit_cast(float, u << 16);
}
__device__ __forceinline__ float bfhi2f(unsigned int u) {
  return __builtin_bit_cast(float, u & 0xffff0000u);
}

// Fast (native v_exp/v_log) log-space terms from (h, g):
//   lc = -softplus(g) ;  lv = -softplus(-g) + log_g(h) = g + lc + log_g(h)
__device__ __forceinline__ void lclv_fast(float h, float g, float& lc, float& lv) {
  float eg = __expf(-fabsf(g));
  float sp = fmaxf(g, 0.f) + __logf(1.f + eg);
  lc = -sp;
  float eh = __expf(h);
  float t  = (h >= 0.f) ? (h + 0.5f) : (1.f + eh);
  float lt = __logf(t);
  float lg = (h >= 0.f) ? lt : (h - lt);
  lv = g + lc + lg;
}
// a may be -inf; b finite
__device__ __forceinline__ float logaddexp_f(float a, float b) {
  float m = fmaxf(a, b);
  return m + __logf(1.f + __expf(-fabsf(a - b)));
}

// async 16B/lane global->LDS; dest = wave-uniform base + lane*16
__device__ __forceinline__ void async_copy16(const ushort_t* g, ushort_t* l) {
  __builtin_amdgcn_global_load_lds(
      (const __attribute__((address_space(1))) void*)g,
      (__attribute__((address_space(3))) void*)l, 16, 0, 0);
}

// ---------------------------------------------------------------------------
// One-time input conversions
// ---------------------------------------------------------------------------
__global__ __launch_bounds__(256) void convert_f32_bf16(
    const float* __restrict__ src, ushort_t* __restrict__ dst) {
  int i = blockIdx.x * 256 + threadIdx.x;   // one float4 per thread
  float4 v = ((const float4*)src)[i];
  u16x4 o = {f2bf(v.x), f2bf(v.y), f2bf(v.z), f2bf(v.w)};
  ((u16x4*)dst)[i] = o;
}

// dst[n][k] = bf16(src[k][n]); src is [K][N] fp32
__global__ __launch_bounds__(256) void transpose_f32_bf16(
    const float* __restrict__ src, ushort_t* __restrict__ dst, int K, int N) {
  __shared__ float tile[32][33];
  int tx = threadIdx.x & 31, ty = threadIdx.x >> 5;   // 32 x 8
  int n0 = blockIdx.x * 32, k0 = blockIdx.y * 32;
#pragma unroll
  for (int i = 0; i < 4; i++) {
    int k = ty + i * 8;
    tile[k][tx] = src[(size_t)(k0 + k) * N + n0 + tx];
  }
  __syncthreads();
#pragma unroll
  for (int i = 0; i < 4; i++) {
    int r = ty + i * 8;
    dst[(size_t)(n0 + r) * K + k0 + tx] = f2bf(tile[tx][r]);
  }
}

// ---------------------------------------------------------------------------
// GEMM1 fused — r2's measured-best version VERBATIM (173.8 us): 256x(128h+
// 128g), 8-wave, 4 phases/K-tile, 3-buf A rotation + 2-buf B, counted
// lgkmcnt micro-groups, counted vmcnt(4), natural block mapping, plain
// lc/lv-pack epilogue. Chunk summaries are computed by scan_phase1 (the
// fused-epilogue variant measured +35 us inside gemm1 vs ~20 us standalone).
// ---------------------------------------------------------------------------
#define G1_NT (DIM / 64)        // 16 K-tiles
#define G2_NT (DIM_INNER / 64)  // 32 K-tiles

__global__ __launch_bounds__(512, 2) void gemm1_fused(
    const ushort_t* __restrict__ Xbf, const ushort_t* __restrict__ Wt,
    unsigned int* __restrict__ LCLV) {
  __shared__ __align__(16) ushort_t lds[81920];   // 160 KB exactly

  const int tid = threadIdx.x;
  const int wv = tid >> 6;
  const int lane = tid & 63;
  const int wr = wv >> 2;           // 0..1 (M half)
  const int wc = wv & 3;            // 0..3 (N quarter)
  const int l15 = lane & 15;
  const int quad = lane >> 4;
  const int n0 = blockIdx.x * 128;  // h-column base (g rows = +DIM_INNER in Wt)
  const int m0 = blockIdx.y * 256;

  // ---- precomputed staging offsets (32-bit; kt*64 added per call, affine)
  int aSrc[2][2], bSrc[2][2];   // [half][L]
  int dstE[2];
#pragma unroll
  for (int L = 0; L < 2; L++) {
    int e = L * 512 + tid;
    int row = e >> 3, slot = e & 7;
    int sw = (slot ^ (row & 7)) << 3;
    dstE[L] = e * 8;
#pragma unroll
    for (int half = 0; half < 2; half++) {
      aSrc[half][L] = (m0 + half * 128 + row) * DIM + sw;
      int br = half * 128 + row;
      int grow = n0 + ((br >> 6) << 5) + (br & 31) + ((br & 32) ? DIM_INNER : 0);
      bSrc[half][L] = grow * DIM + sw;
    }
  }

  auto stageA = [&](int kt, int half, int buf) {
#pragma unroll
    for (int L = 0; L < 2; L++)
      async_copy16(Xbf + aSrc[half][L] + kt * 64,
                   lds + buf * 16384 + half * 8192 + dstE[L]);
  };
  auto stageB = [&](int kt, int half, int buf) {
#pragma unroll
    for (int L = 0; L < 2; L++)
      async_copy16(Wt + bSrc[half][L] + kt * 64,
                   lds + 49152 + buf * 16384 + half * 8192 + dstE[L]);
  };

  // ---- precomputed ds_read bases (swz depends only on ks,quad,l15&7)
  const int swz0 = ((quad ^ (l15 & 7)) << 3);
  const int swz1 = (((4 | quad) ^ (l15 & 7)) << 3);
  const int aB0 = wr * 8192 + l15 * 64 + swz0;
  const int aB1 = wr * 8192 + l15 * 64 + swz1;
  const int bB0 = wc * 4096 + l15 * 64 + swz0;
  const int bB1 = wc * 4096 + l15 * 64 + swz1;

  auto readA = [&](int buf, int mf, int ks) -> bf16x8 {
    const ushort_t* p = lds + buf * 16384 + (ks ? aB1 : aB0) + mf * 1024;
    return __builtin_bit_cast(bf16x8, *(const short8_t*)p);
  };
  auto readB = [&](int buf, int nf, int ks) -> bf16x8 {
    const ushort_t* p = lds + 49152 + buf * 16384 + (ks ? bB1 : bB0) + nf * 1024;
    return __builtin_bit_cast(bf16x8, *(const short8_t*)p);
  };

  floatx4 acc[8][4];
#pragma unroll
  for (int i = 0; i < 8; i++)
#pragma unroll
    for (int j = 0; j < 4; j++) acc[i][j] = (floatx4){0.f, 0.f, 0.f, 0.f};

  bf16x8 aF[4][2], b0F[2][2], b1F[2][2];

  // 4 MFMA: aF[MA] x bX[0..1] -> acc[MC][J], acc[MC][J+1]
  auto mma4 = [&](auto MA, auto MC, auto J, bf16x8 (&bX)[2][2]) {
#pragma unroll
    for (int jj = 0; jj < 2; jj++)
#pragma unroll
      for (int ks = 0; ks < 2; ks++)
        acc[MC.v][J.v + jj] = __builtin_amdgcn_mfma_f32_16x16x32_bf16(
            aF[MA.v][ks], bX[jj][ks], acc[MC.v][J.v + jj], 0, 0, 0);
  };
  // 8 MFMA: aF[0..3] x bvec -> acc[0..3][J]
  auto mmaRow = [&](auto J, bf16x8 (&bvec)[2]) {
#pragma unroll
    for (int m = 0; m < 4; m++)
#pragma unroll
      for (int ks = 0; ks < 2; ks++)
        acc[m][J.v] = __builtin_amdgcn_mfma_f32_16x16x32_bf16(
            aF[m][ks], bvec[ks], acc[m][J.v], 0, 0, 0);
  };

  int bufA = 0, bufB = 0, bufAn = 2, bufBn = 1;

  auto tileBody = [&](int kb, int ka, auto STB, auto STA, auto VMALL) {
    // ---------- phase 0 : Q(mh0 x nh0); stage B(kb) half0
    aF[0][0] = readA(bufA, 0, 0); aF[0][1] = readA(bufA, 0, 1);
    b0F[0][0] = readB(bufB, 0, 0); b0F[0][1] = readB(bufB, 0, 1);
    b0F[1][0] = readB(bufB, 1, 0); b0F[1][1] = readB(bufB, 1, 1);
    SCHED0();
    aF[1][0] = readA(bufA, 1, 0); aF[1][1] = readA(bufA, 1, 1);
    SCHED0();
    aF[2][0] = readA(bufA, 2, 0); aF[2][1] = readA(bufA, 2, 1);
    SCHED0();
    aF[3][0] = readA(bufA, 3, 0); aF[3][1] = readA(bufA, 3, 1);
    SCHED0();
    if constexpr (STB.v) stageB(kb, 0, bufBn);
    SBAR();
    PRIO1();
    LGKM_SB(6); mma4(IC<0>{}, IC<0>{}, IC<0>{}, b0F);
    LGKM_SB(4); mma4(IC<1>{}, IC<1>{}, IC<0>{}, b0F);
    LGKM_SB(2); mma4(IC<2>{}, IC<2>{}, IC<0>{}, b0F);
    LGKM_SB(0); mma4(IC<3>{}, IC<3>{}, IC<0>{}, b0F);
    PRIO0();
    SBAR();

    // ---------- phase 1 : Q(mh0 x nh1); stage B(kb) half1
    b1F[0][0] = readB(bufB, 2, 0); b1F[0][1] = readB(bufB, 2, 1);
    SCHED0();
    b1F[1][0] = readB(bufB, 3, 0); b1F[1][1] = readB(bufB, 3, 1);
    SCHED0();
    if constexpr (STB.v) stageB(kb, 1, bufBn);
    SBAR();
    PRIO1();
    LGKM_SB(2); mmaRow(IC<2>{}, b1F[0]);
    LGKM_SB(0); mmaRow(IC<3>{}, b1F[1]);
    PRIO0();
    SBAR();

    // ---------- phase 2 : Q(mh1 x nh1); stage A(ka) half0
    aF[0][0] = readA(bufA, 4, 0); aF[0][1] = readA(bufA, 4, 1);
    SCHED0();
    aF[1][0] = readA(bufA, 5, 0); aF[1][1] = readA(bufA, 5, 1);
    SCHED0();
    aF[2][0] = readA(bufA, 6, 0); aF[2][1] = readA(bufA, 6, 1);
    SCHED0();
    aF[3][0] = readA(bufA, 7, 0); aF[3][1] = readA(bufA, 7, 1);
    SCHED0();
    if constexpr (STA.v) stageA(ka, 0, bufAn);
    SBAR();
    PRIO1();
    LGKM_SB(6); mma4(IC<0>{}, IC<4>{}, IC<2>{}, b1F);
    LGKM_SB(4); mma4(IC<1>{}, IC<5>{}, IC<2>{}, b1F);
    LGKM_SB(2); mma4(IC<2>{}, IC<6>{}, IC<2>{}, b1F);
    LGKM_SB(0); mma4(IC<3>{}, IC<7>{}, IC<2>{}, b1F);
    PRIO0();
    SBAR();

    // ---------- phase 3 : Q(mh1 x nh0); stage A(ka) half1; counted vmcnt
    if constexpr (STA.v) stageA(ka, 1, bufAn);
    SCHED0();
    if constexpr (STA.v) {
      asm volatile("s_waitcnt vmcnt(4)" ::: "memory");
    } else if constexpr (VMALL.v) {
      asm volatile("s_waitcnt vmcnt(0)" ::: "memory");
    }
    SBAR();
    PRIO1();
    mma4(IC<0>{}, IC<4>{}, IC<0>{}, b0F);
    mma4(IC<1>{}, IC<5>{}, IC<0>{}, b0F);
    mma4(IC<2>{}, IC<6>{}, IC<0>{}, b0F);
    mma4(IC<3>{}, IC<7>{}, IC<0>{}, b0F);
    PRIO0();
    SBAR();
  };

  // prologue: B(0), A(0), A(1); keep A(1)'s 4 loads in flight
  stageB(0, 0, 0); stageB(0, 1, 0);
  stageA(0, 0, 0); stageA(0, 1, 0);
  stageA(1, 0, 1); stageA(1, 1, 1);
  asm volatile("s_waitcnt vmcnt(4)" ::: "memory");
  SBAR();

  for (int u = 0; u < G1_NT - 2; u++) {
    tileBody(u + 1, u + 2, BC<true>{}, BC<true>{}, BC<false>{});
    bufA = (bufA == 2) ? 0 : bufA + 1;
    bufAn = (bufAn == 2) ? 0 : bufAn + 1;
    bufB ^= 1; bufBn ^= 1;
  }
  tileBody(G1_NT - 1, 0, BC<true>{}, BC<false>{}, BC<true>{});
  bufA = (bufA == 2) ? 0 : bufA + 1;
  bufB ^= 1;
  tileBody(0, 0, BC<false>{}, BC<false>{}, BC<false>{});

  // epilogue: (h,g) pairs are acc[mf][j] / acc[mf][j+2], same (row,col)
#pragma unroll
  for (int mf = 0; mf < 8; mf++)
#pragma unroll
    for (int j = 0; j < 2; j++) {
      int col = n0 + wc * 32 + j * 16 + l15;
#pragma unroll
      for (int r = 0; r < 4; r++) {
        int row = m0 + wr * 128 + mf * 16 + quad * 4 + r;
        float lc, lv;
        lclv_fast(acc[mf][j][r], acc[mf][j + 2][r], lc, lv);
        unsigned int pk = ((unsigned int)f2bf(lv) << 16) | (unsigned int)f2bf(lc);
        LCLV[(size_t)row * DIM_INNER + col] = pk;
      }
    }
}

// ---------------------------------------------------------------------------
// GEMM2 — r5's measured-best structure (static dbuf, 8-phase pairBody,
// counted vmcnt(4)/vmcnt(8)): out = H @ W_out, K = 2048 (32 tiles).
// grid = (DIM/256) x (rows/256) = 256 blocks -> 1 per CU.
// ---------------------------------------------------------------------------
#define A0OFF 0
#define A1OFF 16384
#define B0OFF 32768
#define B1OFF 49152

__global__ __launch_bounds__(512, 2) void gemm2(
    const ushort_t* __restrict__ Hbf, const ushort_t* __restrict__ Wot,
    float* __restrict__ OUT) {
  __shared__ __align__(16) ushort_t lds[65536];

  const int tid = threadIdx.x;
  const int lane = tid & 63;
  const int wv = tid >> 6;
  const int wr = wv >> 2;
  const int wc = wv & 3;
  const int l15 = lane & 15;
  const int quad = lane >> 4;
  const int n0 = blockIdx.x * 256;
  const int m0 = blockIdx.y * 256;

  int aSrc[2][2], bSrc[2][2];
  int dstE[2];
#pragma unroll
  for (int L = 0; L < 2; L++) {
    int e = L * 512 + tid;
    int row = e >> 3, slot = e & 7;
    int sw = (slot ^ (row & 7)) << 3;
    dstE[L] = e * 8;
#pragma unroll
    for (int half = 0; half < 2; half++) {
      aSrc[half][L] = (m0 + half * 128 + row) * DIM_INNER + sw;
      bSrc[half][L] = (n0 + half * 128 + row) * DIM_INNER + sw;
    }
  }

  auto stA = [&](int kt, int half, auto AO) {
#pragma unroll
    for (int L = 0; L < 2; L++)
      async_copy16(Hbf + aSrc[half][L] + kt * 64,
                   lds + AO.v + half * 8192 + dstE[L]);
  };
  auto stB = [&](int kt, int half, auto BO) {
#pragma unroll
    for (int L = 0; L < 2; L++)
      async_copy16(Wot + bSrc[half][L] + kt * 64,
                   lds + BO.v + half * 8192 + dstE[L]);
  };

  const int swz0 = ((quad ^ (l15 & 7)) << 3);
  const int swz1 = (((4 | quad) ^ (l15 & 7)) << 3);
  const int aB0 = wr * 8192 + l15 * 64 + swz0;
  const int aB1 = wr * 8192 + l15 * 64 + swz1;
  const int bB0 = wc * 4096 + l15 * 64 + swz0;
  const int bB1 = wc * 4096 + l15 * 64 + swz1;

  floatx4 acc[8][4];
#pragma unroll
  for (int i = 0; i < 8; i++)
#pragma unroll
    for (int j = 0; j < 4; j++) acc[i][j] = (floatx4){0.f, 0.f, 0.f, 0.f};

  bf16x8 aF[4][2], b0F[2][2], b1F[2][2];

  auto rdA4 = [&](auto AO, int mb) {
#pragma unroll
    for (int m = 0; m < 4; m++) {
      aF[m][0] = __builtin_bit_cast(bf16x8,
          *(const short8_t*)(lds + AO.v + aB0 + (mb + m) * 1024));
      aF[m][1] = __builtin_bit_cast(bf16x8,
          *(const short8_t*)(lds + AO.v + aB1 + (mb + m) * 1024));
    }
  };
  auto rdB2 = [&](auto BO, int nb, bf16x8 (&bX)[2][2]) {
#pragma unroll
    for (int n = 0; n < 2; n++) {
      bX[n][0] = __builtin_bit_cast(bf16x8,
          *(const short8_t*)(lds + BO.v + bB0 + (nb + n) * 1024));
      bX[n][1] = __builtin_bit_cast(bf16x8,
          *(const short8_t*)(lds + BO.v + bB1 + (nb + n) * 1024));
    }
  };
  auto mmaQ = [&](auto MB, auto JB, bf16x8 (&bX)[2][2]) {
#pragma unroll
    for (int m = 0; m < 4; m++)
#pragma unroll
      for (int jj = 0; jj < 2; jj++)
#pragma unroll
        for (int ks = 0; ks < 2; ks++)
          acc[MB.v + m][JB.v + jj] = __builtin_amdgcn_mfma_f32_16x16x32_bf16(
              aF[m][ks], bX[jj][ks], acc[MB.v + m][JB.v + jj], 0, 0, 0);
  };

  auto pairBody = [&](int k2, auto STG) {
    rdA4(IC<A0OFF>{}, 0); rdB2(IC<B0OFF>{}, 0, b0F);
    SCHED0();
    SBAR(); LGKM_SB(0);
    PRIO1(); mmaQ(IC<0>{}, IC<0>{}, b0F); PRIO0();
    SBAR();
    rdB2(IC<B0OFF>{}, 2, b1F);
    SCHED0();
    SBAR(); LGKM_SB(0);
    PRIO1(); mmaQ(IC<0>{}, IC<2>{}, b1F); PRIO0();
    SBAR();
    rdA4(IC<A0OFF>{}, 4);
    SCHED0();
    if constexpr (STG.v) stB(k2, 0, IC<B0OFF>{});
    SBAR(); LGKM_SB(0);
    PRIO1(); mmaQ(IC<4>{}, IC<2>{}, b1F); PRIO0();
    SBAR();
    if constexpr (STG.v) {
      stB(k2, 1, IC<B0OFF>{});
      asm volatile("s_waitcnt vmcnt(4)" ::: "memory");
    } else {
      asm volatile("s_waitcnt vmcnt(0)" ::: "memory");
    }
    SBAR();
    PRIO1(); mmaQ(IC<4>{}, IC<0>{}, b0F); PRIO0();
    SBAR();
    rdA4(IC<A1OFF>{}, 0); rdB2(IC<B1OFF>{}, 0, b0F);
    SCHED0();
    if constexpr (STG.v) stA(k2, 0, IC<A0OFF>{});
    SBAR(); LGKM_SB(0);
    PRIO1(); mmaQ(IC<0>{}, IC<0>{}, b0F); PRIO0();
    SBAR();
    rdB2(IC<B1OFF>{}, 2, b1F);
    SCHED0();
    if constexpr (STG.v) stA(k2, 1, IC<A0OFF>{});
    SBAR(); LGKM_SB(0);
    PRIO1(); mmaQ(IC<0>{}, IC<2>{}, b1F); PRIO0();
    SBAR();
    rdA4(IC<A1OFF>{}, 4);
    SCHED0();
    if constexpr (STG.v) stB(k2 + 1, 0, IC<B1OFF>{});
    SBAR(); LGKM_SB(0);
    PRIO1(); mmaQ(IC<4>{}, IC<2>{}, b1F); PRIO0();
    SBAR();
    if constexpr (STG.v) {
      stB(k2 + 1, 1, IC<B1OFF>{});
      stA(k2 + 1, 0, IC<A1OFF>{});
      stA(k2 + 1, 1, IC<A1OFF>{});
      asm volatile("s_waitcnt vmcnt(8)" ::: "memory");
    }
    SBAR();
    PRIO1(); mmaQ(IC<4>{}, IC<0>{}, b0F); PRIO0();
    SBAR();
  };

  stA(0, 0, IC<A0OFF>{}); stA(0, 1, IC<A0OFF>{});
  stB(0, 0, IC<B0OFF>{}); stB(0, 1, IC<B0OFF>{});
  stA(1, 0, IC<A1OFF>{}); stA(1, 1, IC<A1OFF>{});
  stB(1, 0, IC<B1OFF>{}); stB(1, 1, IC<B1OFF>{});
  asm volatile("s_waitcnt vmcnt(8)" ::: "memory");
  SBAR();

  for (int it = 0; it < G2_NT / 2 - 1; ++it)
    pairBody(2 * it + 2, BC<true>{});
  pairBody(0, BC<false>{});

#pragma unroll
  for (int mf = 0; mf < 8; mf++)
#pragma unroll
    for (int j = 0; j < 4; j++) {
      int col = n0 + wc * 64 + (j >> 1) * 32 + (j & 1) * 16 + l15;
#pragma unroll
      for (int r = 0; r < 4; r++) {
        int row = m0 + wr * 128 + mf * 16 + quad * 4 + r;
        OUT[(size_t)row * DIM + col] = acc[mf][j][r];
      }
    }
}

// ---------------------------------------------------------------------------
// Chunked log-space scan
// ---------------------------------------------------------------------------
__global__ __launch_bounds__(256) void scan_phase1(
    const unsigned int* __restrict__ LCLV,
    float* __restrict__ Asum, float* __restrict__ Lend, int nbch) {
  const int EQ = DIM_INNER / 4;               // 512 channel-quads per batch
  int tid = blockIdx.x * 256 + threadIdx.x;   // nb * EQ * NCHUNK
  int ep = tid % EQ;
  int tmp = tid / EQ;
  int c = tmp % NCHUNK;
  int bz = tmp / NCHUNK;
  size_t base4 = ((size_t)bz * SEQ + (size_t)c * CHUNK) * EQ + ep;
  const uint4_t* L4 = (const uint4_t*)LCLV;

  float4_t asum = {0.f, 0.f, 0.f, 0.f};
  float4_t logh = {-INFINITY, -INFINITY, -INFINITY, -INFINITY};
#pragma unroll 4
  for (int t = 0; t < CHUNK; t++) {
    uint4_t u = L4[base4 + (size_t)t * EQ];
#pragma unroll
    for (int k = 0; k < 4; k++) {
      float lc = bflo2f(u[k]), lv = bfhi2f(u[k]);
      asum[k] += lc;
      logh[k] = logaddexp_f(lc + logh[k], lv);
    }
  }
  size_t sidx = ((size_t)c * nbch + (size_t)bz * DIM_INNER) / 4 + ep;
  ((float4_t*)Asum)[sidx] = asum;
  ((float4_t*)Lend)[sidx] = logh;
}

// In-place: Asum[c][ch] -> P[c][ch] (prefix BEFORE chunk c).
// Group-of-8 software pipeline: batch-load 8 (a,le) pairs with STATIC
// indices (rule #20), then compose/store 8 — amortizes the ~400-cycle load
// latency 8x (this kernel is only 128 waves chip-wide, pure latency-bound).
__global__ __launch_bounds__(256) void scan_phase2(
    float* Asum, const float* __restrict__ Lend, int nbch) {
  int ch = blockIdx.x * 256 + threadIdx.x;
  float p = -INFINITY;
  for (int c8 = 0; c8 < NCHUNK; c8 += 8) {
    float a[8], le[8];
#pragma unroll
    for (int i = 0; i < 8; i++) {
      a[i]  = Asum[(size_t)(c8 + i) * nbch + ch];
      le[i] = Lend[(size_t)(c8 + i) * nbch + ch];
    }
#pragma unroll
    for (int i = 0; i < 8; i++) {
      Asum[(size_t)(c8 + i) * nbch + ch] = p;
      p = logaddexp_f(a[i] + p, le[i]);
    }
  }
}

// Rescan with real prefix; write h = exp(log_h) as bf16 into H (8B/lane).
__global__ __launch_bounds__(256) void scan_phase3(
    const unsigned int* __restrict__ LCLV, const float* __restrict__ P,
    ushort_t* __restrict__ H, int nbch) {
  const int EQ = DIM_INNER / 4;
  int tid = blockIdx.x * 256 + threadIdx.x;
  int ep = tid % EQ;
  int tmp = tid / EQ;
  int c = tmp % NCHUNK;
  int bz = tmp / NCHUNK;
  size_t base4 = ((size_t)bz * SEQ + (size_t)c * CHUNK) * EQ + ep;
  const uint4_t* L4 = (const uint4_t*)LCLV;
  u16x4* H4 = (u16x4*)H;

  size_t pidx = ((size_t)c * nbch + (size_t)bz * DIM_INNER) / 4 + ep;
  float4_t logh = ((const float4_t*)P)[pidx];
#pragma unroll 4
  for (int t = 0; t < CHUNK; t++) {
    uint4_t u = L4[base4 + (size_t)t * EQ];
    u16x4 hv;
#pragma unroll
    for (int k = 0; k < 4; k++) {
      float lc = bflo2f(u[k]), lv = bfhi2f(u[k]);
      logh[k] = logaddexp_f(lc + logh[k], lv);
      hv[k] = f2bf(__expf(logh[k]));
    }
    H4[base4 + (size_t)t * EQ] = hv;
  }
}

extern "C" void kernel_launch(void* const* d_in, const int* in_sizes, int n_in,
                              void* d_out, int out_size, void* d_ws, size_t ws_size,
                              hipStream_t stream) {
  const float* X = (const float*)d_in[0];     // [4,4096,1024]
  const float* Whg = (const float*)d_in[1];   // [1024,4096]
  const float* Wout = (const float*)d_in[2];  // [2048,1024]
  float* out = (float*)d_out;                 // [4,4096,1024] fp32

  ushort_t* Xbf = (ushort_t*)d_ws;
  ushort_t* Whg_t = Xbf + (size_t)MTOT * DIM;                   // [4096][1024]
  ushort_t* Wout_t = Whg_t + (size_t)(2 * DIM_INNER) * DIM;     // [1024][2048]
  char* pp = (char*)(Wout_t + (size_t)DIM * DIM_INNER);

  const size_t fixed_bytes = (size_t)MTOT * DIM * 2 +
                             (size_t)2 * DIM_INNER * DIM * 2 +
                             (size_t)DIM * DIM_INNER * 2;
  // per batch: LCLV 4B + H 2B per elem + 2 summaries
  const size_t per_batch = (size_t)SEQ * DIM_INNER * 4 +
                           (size_t)SEQ * DIM_INNER * 2 +
                           2 * (size_t)DIM_INNER * NCHUNK * 4;
  int nb = 4;
  while (nb > 1 && fixed_bytes + (size_t)nb * per_batch > ws_size) nb >>= 1;
  const int npass = BATCH / nb;

  convert_f32_bf16<<<(MTOT * DIM / 4) / 256, 256, 0, stream>>>(X, Xbf);
  transpose_f32_bf16<<<dim3(2 * DIM_INNER / 32, DIM / 32), 256, 0, stream>>>(
      Whg, Whg_t, DIM, 2 * DIM_INNER);
  transpose_f32_bf16<<<dim3(DIM / 32, DIM_INNER / 32), 256, 0, stream>>>(
      Wout, Wout_t, DIM_INNER, DIM);

  for (int pass = 0; pass < npass; pass++) {
    const int b0 = pass * nb;
    const int nrows = nb * SEQ;
    const int nbch = nb * DIM_INNER;

    unsigned int* LCLV = (unsigned int*)pp;
    ushort_t* Hbf = (ushort_t*)(LCLV + (size_t)nb * SEQ * DIM_INNER);
    float* Asum = (float*)(Hbf + (size_t)nb * SEQ * DIM_INNER);
    float* Lend = Asum + (size_t)nb * DIM_INNER * NCHUNK;

    gemm1_fused<<<dim3(DIM_INNER / 128, nrows / 256), 512, 0, stream>>>(
        Xbf + (size_t)b0 * SEQ * DIM, Whg_t, LCLV);
    scan_phase1<<<(nbch / 4 * NCHUNK) / 256, 256, 0, stream>>>(LCLV, Asum, Lend, nbch);
    scan_phase2<<<nbch / 256, 256, 0, stream>>>(Asum, Lend, nbch);
    scan_phase3<<<(nbch / 4 * NCHUNK) / 256, 256, 0, stream>>>(LCLV, Asum, Hbf, nbch);
    gemm2<<<dim3(DIM / 256, nrows / 256), 512, 0, stream>>>(
        Hbf, Wout_t, out + (size_t)b0 * SEQ * DIM);
  }
}